// Round 12
// baseline (329.985 us; speedup 1.0000x reference)
//
#include <hip/hip_runtime.h>
#include <hip/hip_bf16.h>
#include <math.h>

#define NB 32
#define NS 512
#define NH 1024
#define NT 37
#define NLP 39
#define NM (NB*NS)   // 16384

typedef __attribute__((ext_vector_type(8))) short bf16x8;
typedef __attribute__((ext_vector_type(4))) float f32x4;

__device__ __forceinline__ float bf2f(unsigned int u) {
    unsigned int x = u << 16;
    float f;
    __builtin_memcpy(&f, &x, 4);
    return f;
}
__device__ __forceinline__ unsigned short f2bf(float f) {
    __hip_bfloat16 hb = __float2bfloat16(f);
    unsigned short u;
    __builtin_memcpy(&u, &hb, 2);
    return u;
}
__device__ __forceinline__ unsigned int pk2(float lo, float hi) {
    return ((unsigned int)f2bf(hi) << 16) | (unsigned int)f2bf(lo);
}
// bijective XOR swizzle for [row][64B] bf16 LDS tiles
__device__ __forceinline__ int SW64(int b)  { return b ^ ((b >> 2) & 0x70); }
// tile swizzle for [128/256 row][64 k] bf16 tiles (row stride 128B)
__device__ __forceinline__ int TSW(int row, int kcolByte) {
    return (row * 128 + kcolByte) ^ ((row & 7) << 4);
}
__device__ __forceinline__ float rl(float x, int l) {
    return __int_as_float(__builtin_amdgcn_readlane(__float_as_int(x), l));
}
__device__ __forceinline__ void gld16(const void* g, void* l) {
    __builtin_amdgcn_global_load_lds((const __attribute__((address_space(1))) void*)g,
                                     (__attribute__((address_space(3))) void*)l, 16, 0, 0);
}
#define VMW(N) asm volatile("s_waitcnt vmcnt(" #N ")" ::: "memory")
#define BARR() do { __builtin_amdgcn_s_barrier(); __builtin_amdgcn_sched_barrier(0); } while (0)

// ---------------------------------------------------------------------------
// Kernel A1 (v2): scores = h@bio^T /32 -> softmax -> attn (bf16 [NM][64]).
// bio staged ONCE in 96KB LDS; barrier-free K-loop, A-frags from global.
// ---------------------------------------------------------------------------
__global__ __launch_bounds__(512) void kA1(const float* __restrict__ h,
                                           const float* __restrict__ bio,
                                           unsigned short* __restrict__ attn) {
    __shared__ __align__(16) char Bl[48 * 2048];   // 96KB: [t][1024k] bf16, ^(t&7)<<4

    const int tid  = threadIdx.x;
    const int lane = tid & 63;
    const int wid  = tid >> 6;
    const int lr   = lane & 15;
    const int lk   = lane >> 4;
    const int m0   = blockIdx.x * 128;

    for (int idx = tid; idx < 37 * 256; idx += 512) {
        int t = idx >> 8, k4 = idx & 255;
        float4 v = *(const float4*)&bio[(size_t)t * NH + k4 * 4];
        int byte = (t * 2048 + k4 * 8) ^ ((t & 7) << 4);
        *(uint2*)(Bl + byte) = make_uint2(pk2(v.x, v.y), pk2(v.z, v.w));
    }
    for (int idx = tid; idx < 11 * 256; idx += 512) {
        int t = 37 + (idx >> 8), k4 = idx & 255;
        int byte = (t * 2048 + k4 * 8) ^ ((t & 7) << 4);
        *(uint2*)(Bl + byte) = make_uint2(0, 0);
    }
    __syncthreads();

    const int arow = m0 + wid * 16 + lr;
    const float* hp = h + (size_t)arow * NH + lk * 8;

    f32x4 sacc[3];
#pragma unroll
    for (int j = 0; j < 3; ++j) sacc[j] = (f32x4){0.f, 0.f, 0.f, 0.f};

    float4 p0 = *(const float4*)(hp);
    float4 p1 = *(const float4*)(hp + 4);
    for (int kt = 0; kt < NH; kt += 32) {
        float4 c0 = p0, c1 = p1;
        if (kt + 32 < NH) {
            p0 = *(const float4*)(hp + kt + 32);
            p1 = *(const float4*)(hp + kt + 36);
        }
        union { unsigned int u[4]; bf16x8 v; } af;
        af.u[0] = pk2(c0.x, c0.y); af.u[1] = pk2(c0.z, c0.w);
        af.u[2] = pk2(c1.x, c1.y); af.u[3] = pk2(c1.z, c1.w);
#pragma unroll
        for (int nf = 0; nf < 3; ++nf) {
            int t = nf * 16 + lr;
            int byte = (t * 2048 + (kt + lk * 8) * 2) ^ ((t & 7) << 4);
            bf16x8 bf = *(const bf16x8*)(Bl + byte);
            sacc[nf] = __builtin_amdgcn_mfma_f32_16x16x32_bf16(af.v, bf, sacc[nf], 0, 0, 0);
        }
    }

#pragma unroll
    for (int r = 0; r < 4; ++r) {
        const int orow = wid * 16 + lk * 4 + r;
        float s0 = sacc[0][r] * 0.03125f;
        float s1 = sacc[1][r] * 0.03125f;
        float s2 = sacc[2][r] * 0.03125f;
        const bool v2 = (lr < 5);
        float mx = fmaxf(fmaxf(s0, s1), v2 ? s2 : -1e30f);
#pragma unroll
        for (int d = 1; d < 16; d <<= 1) mx = fmaxf(mx, __shfl_xor(mx, d, 64));
        float e0 = __expf(s0 - mx), e1 = __expf(s1 - mx);
        float e2 = v2 ? __expf(s2 - mx) : 0.f;
        float sm = e0 + e1 + e2;
#pragma unroll
        for (int d = 1; d < 16; d <<= 1) sm += __shfl_xor(sm, d, 64);
        float inv = 1.f / sm;
        size_t g = (size_t)(m0 + orow) * 64;
        attn[g + lr]      = f2bf(e0 * inv);
        attn[g + 16 + lr] = f2bf(e1 * inv);
        attn[g + 32 + lr] = f2bf(e2 * inv);
        attn[g + 48 + lr] = 0;
    }
}

// ---------------------------------------------------------------------------
// Kernel A2 (fallback): aware = attn @ bio, plain bf16 row-major out.
// ---------------------------------------------------------------------------
__global__ __launch_bounds__(256) void kA2(const unsigned short* __restrict__ attn,
                                           const float* __restrict__ bio,
                                           unsigned short* __restrict__ aware) {
    __shared__ __align__(16) char Bsl[128 * 64];

    const int tid  = threadIdx.x;
    const int lane = tid & 63;
    const int wid  = tid >> 6;
    const int wm   = (wid >> 1) * 64;
    const int wn   = (wid & 1) * 64;
    const int lr   = lane & 15;
    const int lk   = lane >> 4;
    const int n0   = blockIdx.x * 128;
    const int m0   = blockIdx.y * 128;

    const int bn = tid & 127;
    const int bq = (tid >> 7) * 16;

    f32x4 acc[4][4];
#pragma unroll
    for (int i = 0; i < 4; ++i)
#pragma unroll
        for (int j = 0; j < 4; ++j) acc[i][j] = (f32x4){0.f, 0.f, 0.f, 0.f};

#pragma unroll
    for (int ks = 0; ks < 2; ++ks) {
        unsigned int p[8];
#pragma unroll
        for (int i = 0; i < 8; ++i) {
            int t0 = ks*32 + bq + 2*i;
            float lo = (t0     < NT) ? bio[(size_t)t0 * NH + n0 + bn]       : 0.f;
            float hi = (t0 + 1 < NT) ? bio[(size_t)(t0+1) * NH + n0 + bn]   : 0.f;
            p[i] = pk2(lo, hi);
        }
        __syncthreads();
        *(int4*)(Bsl + SW64(bn*64 + bq*2))      = make_int4(p[0], p[1], p[2], p[3]);
        *(int4*)(Bsl + SW64(bn*64 + bq*2 + 16)) = make_int4(p[4], p[5], p[6], p[7]);
        __syncthreads();

        bf16x8 af[4];
#pragma unroll
        for (int mf = 0; mf < 4; ++mf)
            af[mf] = *(const bf16x8*)(attn + (size_t)(m0 + wm + mf*16 + lr) * 64 + ks*32 + lk*8);
#pragma unroll
        for (int nf = 0; nf < 4; ++nf) {
            bf16x8 bb = *(const bf16x8*)(Bsl + SW64((wn + nf*16 + lr)*64 + lk*16));
#pragma unroll
            for (int mf = 0; mf < 4; ++mf)
                acc[mf][nf] = __builtin_amdgcn_mfma_f32_16x16x32_bf16(af[mf], bb, acc[mf][nf], 0, 0, 0);
        }
    }

#pragma unroll
    for (int mf = 0; mf < 4; ++mf)
#pragma unroll
        for (int nf = 0; nf < 4; ++nf)
#pragma unroll
            for (int r = 0; r < 4; ++r) {
                size_t row = (size_t)(m0 + wm + mf*16 + lk*4 + r);
                aware[row * NH + n0 + wn + nf*16 + lr] = f2bf(acc[mf][nf][r]);
            }
}

// ---------------------------------------------------------------------------
// Kernel A2f (fast): computes aware chunk AND writes the full concat-A
// [h | aware | h*aware] in bf16, tile-major (128x64 tiles) with TSW swizzle.
// ---------------------------------------------------------------------------
__global__ __launch_bounds__(256) void kA2f(const unsigned short* __restrict__ attn,
                                            const float* __restrict__ bio,
                                            const float* __restrict__ h,
                                            char* __restrict__ Asw) {
    __shared__ __align__(16) char Bsl[128 * 64];
    __shared__ __align__(16) unsigned short awL[128 * 128];  // 32KB aware chunk

    const int tid  = threadIdx.x;
    const int lane = tid & 63;
    const int wid  = tid >> 6;
    const int wm   = (wid >> 1) * 64;
    const int wn   = (wid & 1) * 64;
    const int lr   = lane & 15;
    const int lk   = lane >> 4;
    const int n0   = blockIdx.x * 128;
    const int m0   = blockIdx.y * 128;
    const int tm   = blockIdx.y;

    const int bn = tid & 127;
    const int bq = (tid >> 7) * 16;

    f32x4 acc[4][4];
#pragma unroll
    for (int i = 0; i < 4; ++i)
#pragma unroll
        for (int j = 0; j < 4; ++j) acc[i][j] = (f32x4){0.f, 0.f, 0.f, 0.f};

#pragma unroll
    for (int ks = 0; ks < 2; ++ks) {
        unsigned int p[8];
#pragma unroll
        for (int i = 0; i < 8; ++i) {
            int t0 = ks*32 + bq + 2*i;
            float lo = (t0     < NT) ? bio[(size_t)t0 * NH + n0 + bn]       : 0.f;
            float hi = (t0 + 1 < NT) ? bio[(size_t)(t0+1) * NH + n0 + bn]   : 0.f;
            p[i] = pk2(lo, hi);
        }
        __syncthreads();
        *(int4*)(Bsl + SW64(bn*64 + bq*2))      = make_int4(p[0], p[1], p[2], p[3]);
        *(int4*)(Bsl + SW64(bn*64 + bq*2 + 16)) = make_int4(p[4], p[5], p[6], p[7]);
        __syncthreads();

        bf16x8 af[4];
#pragma unroll
        for (int mf = 0; mf < 4; ++mf)
            af[mf] = *(const bf16x8*)(attn + (size_t)(m0 + wm + mf*16 + lr) * 64 + ks*32 + lk*8);
#pragma unroll
        for (int nf = 0; nf < 4; ++nf) {
            bf16x8 bb = *(const bf16x8*)(Bsl + SW64((wn + nf*16 + lr)*64 + lk*16));
#pragma unroll
            for (int mf = 0; mf < 4; ++mf)
                acc[mf][nf] = __builtin_amdgcn_mfma_f32_16x16x32_bf16(af[mf], bb, acc[mf][nf], 0, 0, 0);
        }
    }

#pragma unroll
    for (int mf = 0; mf < 4; ++mf)
#pragma unroll
        for (int nf = 0; nf < 4; ++nf)
#pragma unroll
            for (int r = 0; r < 4; ++r)
                awL[(wm + mf*16 + lk*4 + r) * 128 + wn + nf*16 + lr] = f2bf(acc[mf][nf][r]);
    __syncthreads();

    // region 1 (aware)
#pragma unroll
    for (int i = 0; i < 8; ++i) {
        int lin = tid + i * 256;
        int row = lin >> 4, kg = lin & 15;
        uint4 v = *(const uint4*)&awL[row * 128 + kg * 8];
        int kglob = 1024 + n0 + kg * 8;
        size_t tbase = ((size_t)tm * 48 + (kglob >> 6)) * 16384;
        *(uint4*)(Asw + tbase + TSW(row, (kglob & 63) * 2)) = v;
    }
    // regions 0 (h) and 2 (h*aware)
#pragma unroll
    for (int i = 0; i < 8; ++i) {
        int lin = tid + i * 256;
        int row = lin >> 4, kg = lin & 15;
        const float4* hp = (const float4*)&h[(size_t)(m0 + row) * NH + n0 + kg * 8];
        float4 ha = hp[0], hb = hp[1];
        float hv[8] = {ha.x, ha.y, ha.z, ha.w, hb.x, hb.y, hb.z, hb.w};
        uint4 awv = *(const uint4*)&awL[row * 128 + kg * 8];
        unsigned int awu[4] = {awv.x, awv.y, awv.z, awv.w};
        unsigned int p0[4], p2[4];
#pragma unroll
        for (int j = 0; j < 4; ++j) {
            p0[j] = pk2(hv[2*j], hv[2*j+1]);
            float lo = hv[2*j]   * bf2f(awu[j] & 0xffffu);
            float hi = hv[2*j+1] * bf2f(awu[j] >> 16);
            p2[j] = pk2(lo, hi);
        }
        int k0g = n0 + kg * 8;
        size_t tb0 = ((size_t)tm * 48 + (k0g >> 6)) * 16384;
        *(uint4*)(Asw + tb0 + TSW(row, (k0g & 63) * 2)) = make_uint4(p0[0], p0[1], p0[2], p0[3]);
        int k2g = 2048 + n0 + kg * 8;
        size_t tb2 = ((size_t)tm * 48 + (k2g >> 6)) * 16384;
        *(uint4*)(Asw + tb2 + TSW(row, (k2g & 63) * 2)) = make_uint4(p2[0], p2[1], p2[2], p2[3]);
    }
}

// ---------------------------------------------------------------------------
// Kernel W: WbT swizzled tiles: W^T[n][k] bf16, tile (tn,tk) = [128 n][64 k].
// ---------------------------------------------------------------------------
__global__ __launch_bounds__(256) void kW(const float* __restrict__ Wcat,
                                          char* __restrict__ Wsw) {
    __shared__ unsigned short wt[64 * 128];

    const int tid  = threadIdx.x;
    const int tile = blockIdx.x;
    const int tn   = tile / 48;
    const int tk   = tile - tn * 48;
    const int n00  = tn * 128;
    const int k0   = tk * 64;

#pragma unroll
    for (int i = 0; i < 8; ++i) {
        int lin = tid + i * 256;
        int kk = lin >> 5, ng = lin & 31;
        float4 v = *(const float4*)&Wcat[(size_t)(k0 + kk) * NH + n00 + ng * 4];
        unsigned int lo = pk2(v.x, v.y), hi = pk2(v.z, v.w);
        *(uint2*)&wt[kk * 128 + ng * 4] = make_uint2(lo, hi);
    }
    __syncthreads();
#pragma unroll
    for (int i = 0; i < 4; ++i) {
        int lin = tid + i * 256;
        int rn = lin >> 3, kg = lin & 7;
        unsigned short t8[8];
#pragma unroll
        for (int j = 0; j < 8; ++j) t8[j] = wt[(kg * 8 + j) * 128 + rn];
        uint4 v = *(const uint4*)t8;
        *(uint4*)(Wsw + (size_t)tile * 16384 + TSW(rn, kg * 16)) = v;
    }
}

// ---------------------------------------------------------------------------
// Kernel W2: prepack Wcrf^T as bf16 [48][3072], rows t>=37 zeroed.
// ---------------------------------------------------------------------------
__global__ __launch_bounds__(256) void kW2(const float* __restrict__ Wcrf,
                                           unsigned short* __restrict__ WT) {
    const int idx = blockIdx.x * 256 + threadIdx.x;   // 48*384 = 18432
    if (idx >= 48 * 384) return;
    const int t = idx / 384, kg = idx - t * 384;
    unsigned short v[8];
#pragma unroll
    for (int e = 0; e < 8; ++e) {
        int k = kg * 8 + e;
        v[e] = (t < NT) ? f2bf(Wcrf[(size_t)k * NT + t]) : (unsigned short)0;
    }
    uint4 w;
    __builtin_memcpy(&w, v, 16);
    *(uint4*)(WT + (size_t)t * 3072 + kg * 8) = w;
}

// ---------------------------------------------------------------------------
// Kernel Bf (fast): 256x256 tile bf16 GEMM, BK=64, 8 waves, counted-vmcnt
// 4-phase schedule + fused kC epilogue (prepacked Wcrf^T). (round-11 proven)
// ---------------------------------------------------------------------------
__global__ __launch_bounds__(512, 2) void kBf(const char* __restrict__ Asw,
                                              const char* __restrict__ Wsw,
                                              const float* __restrict__ bcat,
                                              const unsigned short* __restrict__ WT,
                                              float* __restrict__ P) {
    __shared__ __align__(16) char lds[131072];  // A: buf*32768+h*16384; B at +65536

    const int tid  = threadIdx.x;
    const int lane = tid & 63;
    const int wid  = tid >> 6;
    const int widm = wid >> 2;       // 0..1
    const int widn = wid & 3;        // 0..3
    const int lr   = lane & 15;
    const int lk   = lane >> 4;

    const int id   = blockIdx.x;     // 256 blocks
    const int xcd  = id & 7;
    const int slot = id >> 3;        // 0..31
    const int Mt   = xcd * 8 + (slot >> 2);
    const int Nt   = slot & 3;
    const int m0   = Mt * 256, n0 = Nt * 256;
    const int soff = tid * 16;

    f32x4 acc00[4][2], acc01[4][2], acc10[4][2], acc11[4][2];
#pragma unroll
    for (int i = 0; i < 4; ++i)
#pragma unroll
        for (int j = 0; j < 2; ++j) {
            acc00[i][j] = (f32x4){0.f,0.f,0.f,0.f};
            acc01[i][j] = (f32x4){0.f,0.f,0.f,0.f};
            acc10[i][j] = (f32x4){0.f,0.f,0.f,0.f};
            acc11[i][j] = (f32x4){0.f,0.f,0.f,0.f};
        }

    auto stageHalf = [&](int T, int ph) {
        const bool isA = (ph == 0) || (ph == 3);
        const int  h   = isA ? (ph == 3 ? 1 : 0) : (ph - 1);
        const char* src = isA
            ? Asw + ((size_t)((2*Mt + h) * 48 + T)) * 16384
            : Wsw + ((size_t)((2*Nt + h) * 48 + T)) * 16384;
        char* dst = lds + (isA ? 0 : 65536) + (T & 1) * 32768 + h * 16384;
        gld16(src + soff,        dst + soff);
        gld16(src + soff + 8192, dst + soff + 8192);
    };
    auto loadA = [&](bf16x8 (&af)[4][2], int q, int half) {
        const char* base = lds + q * 32768 + half * 16384;
#pragma unroll
        for (int i = 0; i < 4; ++i) {
            int row = widm * 64 + i * 16 + lr;
#pragma unroll
            for (int kk = 0; kk < 2; ++kk)
                af[i][kk] = *(const bf16x8*)(base + TSW(row, kk * 64 + lk * 16));
        }
    };
    auto loadB = [&](bf16x8 (&bfr)[2][2], int q, int half) {
        const char* base = lds + 65536 + q * 32768 + half * 16384;
#pragma unroll
        for (int j = 0; j < 2; ++j) {
            int col = widn * 32 + j * 16 + lr;
#pragma unroll
            for (int kk = 0; kk < 2; ++kk)
                bfr[j][kk] = *(const bf16x8*)(base + TSW(col, kk * 64 + lk * 16));
        }
    };
    auto mma = [&](f32x4 (&ac)[4][2], bf16x8 (&af)[4][2], bf16x8 (&bfr)[2][2]) {
        __builtin_amdgcn_s_setprio(1);
#pragma unroll
        for (int kk = 0; kk < 2; ++kk)
#pragma unroll
            for (int i = 0; i < 4; ++i)
#pragma unroll
                for (int j = 0; j < 2; ++j)
                    ac[i][j] = __builtin_amdgcn_mfma_f32_16x16x32_bf16(
                        af[i][kk], bfr[j][kk], ac[i][j], 0, 0, 0);
        __builtin_amdgcn_s_setprio(0);
    };

    stageHalf(0, 0); stageHalf(0, 1); stageHalf(0, 2); stageHalf(0, 3);
    VMW(0);
    BARR();

    for (int T = 0; T < 47; ++T) {
        const int q = T & 1;
        bf16x8 af0[4][2], af1[4][2], bf0[2][2], bf1[2][2];
        stageHalf(T + 1, 0);
        VMW(6);
        BARR();
        loadA(af0, q, 0); loadB(bf0, q, 0);
        mma(acc00, af0, bf0);
        stageHalf(T + 1, 1);
        VMW(6);
        BARR();
        loadB(bf1, q, 1);
        mma(acc01, af0, bf1);
        stageHalf(T + 1, 2);
        VMW(6);
        BARR();
        loadA(af1, q, 1);
        mma(acc10, af1, bf0);
        stageHalf(T + 1, 3);
        BARR();
        mma(acc11, af1, bf1);
    }
    {   // T = 47 (buf 1), tail waits 4/2/0
        const int q = 1;
        bf16x8 af0[4][2], af1[4][2], bf0[2][2], bf1[2][2];
        VMW(4);
        BARR();
        loadA(af0, q, 0); loadB(bf0, q, 0);
        mma(acc00, af0, bf0);
        VMW(2);
        BARR();
        loadB(bf1, q, 1);
        mma(acc01, af0, bf1);
        VMW(0);
        BARR();
        loadA(af1, q, 1);
        mma(acc10, af1, bf0);
        BARR();
        mma(acc11, af1, bf1);
    }

    // ---------------- fused kC epilogue ----------------
    __syncthreads();
    auto stashQ = [&](f32x4 (&ac)[4][2], int a, int b) {
#pragma unroll
        for (int j = 0; j < 2; ++j) {
            const int lcol = b * 128 + widn * 32 + j * 16 + lr;
            const int kc = lcol >> 6, kk = lcol & 63;
            const float bc = bcat[n0 + lcol];
#pragma unroll
            for (int i = 0; i < 4; ++i)
#pragma unroll
                for (int r = 0; r < 4; ++r) {
                    int lrow = a * 128 + widm * 64 + i * 16 + lk * 4 + r;
                    float x = ac[i][j][r] + bc;
                    float g = 0.5f * x * (1.0f + erff(x * 0.70710678118654752f));
                    *(unsigned short*)(lds + kc * 32768 + TSW(lrow, kk * 2)) = f2bf(g);
                }
        }
    };
    stashQ(acc00, 0, 0); stashQ(acc01, 0, 1); stashQ(acc10, 1, 0); stashQ(acc11, 1, 1);
    __syncthreads();

    bf16x8 wfrag[3][8];
#pragma unroll
    for (int tt = 0; tt < 3; ++tt) {
        const int t = tt * 16 + lr;
#pragma unroll
        for (int ks = 0; ks < 8; ++ks)
            wfrag[tt][ks] = *(const bf16x8*)(WT + (size_t)t * 3072 + n0 + ks * 32 + lk * 8);
    }

    f32x4 pacc[2][3];
#pragma unroll
    for (int i = 0; i < 2; ++i)
#pragma unroll
        for (int j = 0; j < 3; ++j) pacc[i][j] = (f32x4){0.f, 0.f, 0.f, 0.f};
#pragma unroll
    for (int rt2 = 0; rt2 < 2; ++rt2) {
        const int lrow = wid * 32 + rt2 * 16 + lr;
#pragma unroll
        for (int ks = 0; ks < 8; ++ks) {
            const int kc = ks >> 1, kh = ks & 1;
            bf16x8 af = *(const bf16x8*)(lds + kc * 32768 + TSW(lrow, kh * 64 + lk * 16));
#pragma unroll
            for (int tt = 0; tt < 3; ++tt)
                pacc[rt2][tt] = __builtin_amdgcn_mfma_f32_16x16x32_bf16(
                    af, wfrag[tt][ks], pacc[rt2][tt], 0, 0, 0);
        }
    }

    float* Pb = P + (size_t)Nt * NM * 48;
#pragma unroll
    for (int rt2 = 0; rt2 < 2; ++rt2)
#pragma unroll
        for (int tt = 0; tt < 3; ++tt)
#pragma unroll
            for (int r = 0; r < 4; ++r) {
                int row = Mt * 256 + wid * 32 + rt2 * 16 + lk * 4 + r;
                Pb[(size_t)row * 48 + tt * 16 + lr] = pacc[rt2][tt][r];
            }
}

// ---------------------------------------------------------------------------
// Kernel Cr: out = sum_Nt P[Nt] + b_crf, pads -10000.
// ---------------------------------------------------------------------------
__global__ __launch_bounds__(256) void kCr(const float* __restrict__ P,
                                           const float* __restrict__ bcrf,
                                           float* __restrict__ out) {
    const int g = blockIdx.x * 256 + threadIdx.x;
    const size_t STRIDE = (size_t)NM * 48;
#pragma unroll
    for (int s = 0; s < 12; ++s) {
        int flat = g * 12 + s;
        int row = flat / 48, t = flat - row * 48;
        float v = P[flat] + P[STRIDE + flat] + P[2*STRIDE + flat] + P[3*STRIDE + flat];
        if (t < NT)       out[(size_t)row * NLP + t] = v + bcrf[t];
        else if (t < NLP) out[(size_t)row * NLP + t] = -10000.0f;
    }
}

// ---------------------------------------------------------------------------
// Kernel B (fallback): reg-staged mixed GEMM (round-4 version).
// ---------------------------------------------------------------------------
__global__ __launch_bounds__(256) void kB(const float* __restrict__ h,
                                          const unsigned short* __restrict__ aware,
                                          const float* __restrict__ Wcat,
                                          const float* __restrict__ bcat,
                                          unsigned short* __restrict__ x2) {
    __shared__ __align__(16) char lds[16384];
    char* Asl = lds;
    char* Bsl = lds + 8192;

    const int tid  = threadIdx.x;
    const int lane = tid & 63;
    const int wid  = tid >> 6;
    const int wm   = (wid >> 1) * 64;
    const int wn   = (wid & 1) * 64;
    const int lr   = lane & 15;
    const int lk   = lane >> 4;

    const int id   = blockIdx.x;
    const int xcd  = id & 7;
    const int slot = id >> 3;
    const int m0   = (xcd * 16 + (slot >> 3)) * 128;
    const int n0   = (slot & 7) * 128;

    const int am = tid >> 1;
    const int ak = (tid & 1) * 16;
    const int bn = tid & 127;
    const int bk = (tid >> 7) * 16;

    f32x4 acc[4][4];
#pragma unroll
    for (int i = 0; i < 4; ++i)
#pragma unroll
        for (int j = 0; j < 4; ++j) acc[i][j] = (f32x4){0.f, 0.f, 0.f, 0.f};

    const float*          hrow = h     + (size_t)(m0 + am) * NH + ak;
    const unsigned short* arow = aware + (size_t)(m0 + am) * NH + ak;
    const float*          wcol = Wcat  + (size_t)bk * NH + n0 + bn;

    float hv[16];
    unsigned int aw[8];
    float wv[16];

    auto stage = [&](int kt) {
        const int region = kt >> 10;
        const int kb = kt & 1023;
        if (region != 1) {
            const float4* hp = (const float4*)(hrow + kb);
            float4 a = hp[0], b = hp[1], c = hp[2], d = hp[3];
            hv[0]=a.x; hv[1]=a.y; hv[2]=a.z; hv[3]=a.w;
            hv[4]=b.x; hv[5]=b.y; hv[6]=b.z; hv[7]=b.w;
            hv[8]=c.x; hv[9]=c.y; hv[10]=c.z; hv[11]=c.w;
            hv[12]=d.x; hv[13]=d.y; hv[14]=d.z; hv[15]=d.w;
        }
        if (region >= 1) {
            const uint4* ap = (const uint4*)(arow + kb);
            uint4 a0 = ap[0], a1 = ap[1];
            aw[0]=a0.x; aw[1]=a0.y; aw[2]=a0.z; aw[3]=a0.w;
            aw[4]=a1.x; aw[5]=a1.y; aw[6]=a1.z; aw[7]=a1.w;
        }
        {
            const float* wp = wcol + (size_t)kt * NH;
#pragma unroll
            for (int j = 0; j < 16; ++j) wv[j] = wp[(size_t)j * NH];
        }
    };

    auto writeStage = [&](int kt) {
        const int region = kt >> 10;
        unsigned int p[8];
        if (region == 0) {
#pragma unroll
            for (int i = 0; i < 8; ++i) p[i] = pk2(hv[2*i], hv[2*i+1]);
        } else if (region == 1) {
#pragma unroll
            for (int i = 0; i < 8; ++i) p[i] = aw[i];
        } else {
#pragma unroll
            for (int i = 0; i < 8; ++i) {
                float lo = hv[2*i]   * bf2f(aw[i] & 0xffffu);
                float hi = hv[2*i+1] * bf2f(aw[i] >> 16);
                p[i] = pk2(lo, hi);
            }
        }
        *(int4*)(Asl + SW64(am*64 + ak*2))      = make_int4(p[0], p[1], p[2], p[3]);
        *(int4*)(Asl + SW64(am*64 + ak*2 + 16)) = make_int4(p[4], p[5], p[6], p[7]);
        unsigned int q[8];
#pragma unroll
        for (int i = 0; i < 8; ++i) q[i] = pk2(wv[2*i], wv[2*i+1]);
        *(int4*)(Bsl + SW64(bn*64 + bk*2))      = make_int4(q[0], q[1], q[2], q[3]);
        *(int4*)(Bsl + SW64(bn*64 + bk*2 + 16)) = make_int4(q[4], q[5], q[6], q[7]);
    };

    stage(0);
    for (int kt = 0; kt < 3072; kt += 32) {
        __syncthreads();
        writeStage(kt);
        __syncthreads();
        if (kt + 32 < 3072) stage(kt + 32);

        bf16x8 af[4], bfr[4];
#pragma unroll
        for (int mf = 0; mf < 4; ++mf)
            af[mf] = *(const bf16x8*)(Asl + SW64((wm + mf*16 + lr)*64 + lk*16));
#pragma unroll
        for (int nf = 0; nf < 4; ++nf)
            bfr[nf] = *(const bf16x8*)(Bsl + SW64((wn + nf*16 + lr)*64 + lk*16));
#pragma unroll
        for (int mf = 0; mf < 4; ++mf)
#pragma unroll
            for (int nf = 0; nf < 4; ++nf)
                acc[mf][nf] = __builtin_amdgcn_mfma_f32_16x16x32_bf16(af[mf], bfr[nf], acc[mf][nf], 0, 0, 0);
    }

#pragma unroll
    for (int nf = 0; nf < 4; ++nf) {
        const int col = n0 + wn + nf*16 + lr;
        const float bc = bcat[col];
#pragma unroll
        for (int mf = 0; mf < 4; ++mf)
#pragma unroll
            for (int r = 0; r < 4; ++r) {
                size_t row = (size_t)(m0 + wm + mf*16 + lk*4 + r);
                float x = acc[mf][nf][r] + bc;
                float g = 0.5f * x * (1.0f + erff(x * 0.70710678118654752f));
                x2[row * NH + col] = f2bf(g);
            }
    }
}

// ---------------------------------------------------------------------------
// Kernel C (fallback): ner_scores = [x2 @ W_crf + b_crf, -10000, -10000]
// ---------------------------------------------------------------------------
__global__ __launch_bounds__(256) void kC(const unsigned short* __restrict__ x2,
                                          const float* __restrict__ Wcrf,
                                          const float* __restrict__ bcrf,
                                          float* __restrict__ out) {
    __shared__ __align__(16) char Asl[8192];
    __shared__ __align__(16) char Bsl[3072];

    const int tid  = threadIdx.x;
    const int lane = tid & 63;
    const int wid  = tid >> 6;
    const int lr   = lane & 15;
    const int lk   = lane >> 4;
    const int m0   = blockIdx.x * 128;
    const int am   = tid >> 1;
    const int ak   = (tid & 1) * 16;

    for (int i = tid; i < 192; i += 256) *(int4*)(Bsl + i*16) = make_int4(0, 0, 0, 0);

    f32x4 acc[2][3];
#pragma unroll
    for (int i = 0; i < 2; ++i)
#pragma unroll
        for (int j = 0; j < 3; ++j) acc[i][j] = (f32x4){0.f, 0.f, 0.f, 0.f};

    const unsigned short* xrow = x2 + (size_t)(m0 + am) * NH + ak;

    for (int kt = 0; kt < NH; kt += 32) {
        const uint4* xp = (const uint4*)(xrow + kt);
        uint4 x0 = xp[0], x1 = xp[1];
        float wv[5];
#pragma unroll
        for (int p = 0; p < 5; ++p) {
            int i = tid + p * 256;
            wv[p] = (i < 32*NT) ? Wcrf[(size_t)kt * NT + i] : 0.f;
        }
        __syncthreads();
        *(uint4*)(Asl + SW64(am*64 + ak*2))      = x0;
        *(uint4*)(Asl + SW64(am*64 + ak*2 + 16)) = x1;
#pragma unroll
        for (int p = 0; p < 5; ++p) {
            int i = tid + p * 256;
            if (i < 32*NT) {
                int kk = i / NT;
                int t  = i - kk * NT;
                *(unsigned short*)(Bsl + SW64(t*64 + kk*2)) = f2bf(wv[p]);
            }
        }
        __syncthreads();
        bf16x8 af[2], bfr[3];
#pragma unroll
        for (int mf = 0; mf < 2; ++mf)
            af[mf] = *(const bf16x8*)(Asl + SW64((wid*32 + mf*16 + lr)*64 + lk*16));
#pragma unroll
        for (int nf = 0; nf < 3; ++nf)
            bfr[nf] = *(const bf16x8*)(Bsl + SW64((nf*16 + lr)*64 + lk*16));
#pragma unroll
        for (int mf = 0; mf < 2; ++mf)
#pragma unroll
            for (int nf = 0; nf < 3; ++nf)
                acc[mf][nf] = __builtin_amdgcn_mfma_f32_16x16x32_bf16(af[mf], bfr[nf], acc[mf][nf], 0, 0, 0);
    }

#pragma unroll
    for (int nf = 0; nf < 3; ++nf) {
        const int t = nf*16 + lr;
        const float bc = (t < NT) ? bcrf[t] : 0.f;
#pragma unroll
        for (int mf = 0; mf < 2; ++mf)
#pragma unroll
            for (int r = 0; r < 4; ++r) {
                size_t row = (size_t)(m0 + wid*32 + mf*16 + lk*4 + r);
                if (t < NT)       out[row * NLP + t] = acc[mf][nf][r] + bc;
                else if (t < NLP) out[row * NLP + t] = -10000.0f;
            }
    }
}

// ---------------------------------------------------------------------------
// Kernel D (v3): CRF log-likelihood. ONE WAVE per block handles TWO batches
// with interleaved scans (batch B's fma chains fill batch A's readlane
// dependency bubbles). Scores staged as bf16 in LDS (2 x 39KB); gold path
// computed exactly from global fp32.
// ---------------------------------------------------------------------------
#define RLBATCH(AS, A)                                        \
    _Pragma("unroll")                                         \
    for (int f_ = 0; f_ < 37; ++f_) AS[f_] = rl(A, f_);

#define FMACHAIN(A, AS, EL) do {                              \
    float c0 = 0.f, c1 = 0.f, c2 = 0.f, c3 = 0.f;             \
    _Pragma("unroll")                                         \
    for (int f_ = 0; f_ < 36; f_ += 4) {                      \
        c0 = fmaf(AS[f_    ], trow[f_    ], c0);              \
        c1 = fmaf(AS[f_ + 1], trow[f_ + 1], c1);              \
        c2 = fmaf(AS[f_ + 2], trow[f_ + 2], c2);              \
        c3 = fmaf(AS[f_ + 3], trow[f_ + 3], c3);              \
    }                                                         \
    c0 = fmaf(AS[36], trow[36], c0);                          \
    A = (EL) * ((c0 + c1) + (c2 + c3));                       \
} while (0)

#define STEP2(EL0, EL1) do {                                  \
    float as0_[37], as1_[37];                                 \
    RLBATCH(as0_, a0); RLBATCH(as1_, a1);                     \
    __builtin_amdgcn_sched_barrier(0);                        \
    FMACHAIN(a0, as0_, EL0); FMACHAIN(a1, as1_, EL1);         \
} while (0)

#define STEP1(A, EL) do {                                     \
    float as_[37];                                            \
    RLBATCH(as_, A);                                          \
    __builtin_amdgcn_sched_barrier(0);                        \
    FMACHAIN(A, as_, EL);                                     \
} while (0)

__global__ __launch_bounds__(64) void kD(const float* __restrict__ scores,
                                         const int* __restrict__ labels,
                                         const int* __restrict__ lens,
                                         const float* __restrict__ trans,
                                         float* __restrict__ loss) {
    __shared__ unsigned short S0[NS * NLP];   // 39936 B, bf16 [t][39]
    __shared__ unsigned short S1[NS * NLP];   // 39936 B
    __shared__ float trL[39 * 41];            // 6396 B

    const int b0   = blockIdx.x * 2;
    const int b1   = b0 + 1;
    const int lane = threadIdx.x;
    const int len0 = lens[b0];
    const int len1 = lens[b1];
    const float* sb0 = scores + (size_t)b0 * NS * NLP;
    const float* sb1 = scores + (size_t)b1 * NS * NLP;

    // stage scores -> bf16 LDS (flat float4 -> uint2)
    for (int i = lane; i < NS * NLP / 4; i += 64) {
        float4 v0 = ((const float4*)sb0)[i];
        float4 v1 = ((const float4*)sb1)[i];
        *(uint2*)&S0[i * 4] = make_uint2(pk2(v0.x, v0.y), pk2(v0.z, v0.w));
        *(uint2*)&S1[i * 4] = make_uint2(pk2(v1.x, v1.y), pk2(v1.z, v1.w));
    }
    for (int idx = lane; idx < 39 * 39; idx += 64) {
        int to = idx / 39, f = idx - to * 39;
        trL[to * 41 + f] = trans[idx];
    }
    __syncthreads();

    // gold paths (exact, fp32 from global; parallel across 64 lanes)
    float g0 = 0.f, g1 = 0.f;
    for (int t = lane; t < len0; t += 64) g0 += sb0[(size_t)t * NLP + labels[b0 * NS + t]];
    for (int t = lane; t < len1; t += 64) g1 += sb1[(size_t)t * NLP + labels[b1 * NS + t]];
    for (int i = lane; i <= len0; i += 64) {
        int frm = (i == 0) ? 37 : labels[b0 * NS + i - 1];
        int to  = (i == len0) ? 38 : labels[b0 * NS + i];
        g0 += trL[to * 41 + frm];
    }
    for (int i = lane; i <= len1; i += 64) {
        int frm = (i == 0) ? 37 : labels[b1 * NS + i - 1];
        int to  = (i == len1) ? 38 : labels[b1 * NS + i];
        g1 += trL[to * 41 + frm];
    }
#pragma unroll
    for (int off = 32; off > 0; off >>= 1) {
        g0 += __shfl_xor(g0, off, 64);
        g1 += __shfl_xor(g1, off, 64);
    }

    const int myrow = (lane < 39) ? lane : 0;
    float trow[39];
#pragma unroll
    for (int f = 0; f < 39; ++f) trow[f] = __expf(trL[myrow * 41 + f]);
    const float trEnd = (lane < 39) ? trL[38 * 41 + lane] : 0.f;
    const bool act = (lane < 39);
    const int lcol = act ? lane : 0;

    auto ld0 = [&](int r) {
        r = (r < len0) ? r : (len0 - 1);
        return bf2f((unsigned int)S0[r * NLP + lcol]);
    };
    auto ld1 = [&](int r) {
        r = (r < len1) ? r : (len1 - 1);
        return bf2f((unsigned int)S1[r * NLP + lcol]);
    };

    // t = 0 closed form
    float a0 = act ? __expf(ld0(0)) * trow[37] : 0.f;
    float a1 = act ? __expf(ld1(0)) * trow[37] : 0.f;
    float C0 = 0.f, C1 = 0.f;

    float lgA0 = ld0(1), lgA1 = ld0(2), lgA2 = ld0(3), lgA3 = ld0(4);
    float lgB0 = ld1(1), lgB1 = ld1(2), lgB2 = ld1(3), lgB3 = ld1(4);

    const int mn = (len0 < len1) ? len0 : len1;
    int t = 1;
    for (; t + 3 < mn; t += 4) {
        float eA0 = __expf(lgA0), eA1 = __expf(lgA1), eA2 = __expf(lgA2), eA3 = __expf(lgA3);
        float eB0 = __expf(lgB0), eB1 = __expf(lgB1), eB2 = __expf(lgB2), eB3 = __expf(lgB3);
        lgA0 = ld0(t + 4); lgA1 = ld0(t + 5); lgA2 = ld0(t + 6); lgA3 = ld0(t + 7);
        lgB0 = ld1(t + 4); lgB1 = ld1(t + 5); lgB2 = ld1(t + 6); lgB3 = ld1(t + 7);
        STEP2(eA0, eB0); STEP2(eA1, eB1); STEP2(eA2, eB2); STEP2(eA3, eB3);
        float s0 = rl(a0, 0), s1 = rl(a1, 0);          // a[0] > 0 always
        float r0 = __builtin_amdgcn_rcpf(s0), r1 = __builtin_amdgcn_rcpf(s1);
        a0 *= r0; C0 -= __logf(r0);
        a1 *= r1; C1 -= __logf(r1);
    }
    for (; t < mn; ++t) {
        STEP1(a0, __expf(ld0(t)));
        STEP1(a1, __expf(ld1(t)));
        if ((t & 3) == 3) {
            float s0 = rl(a0, 0), s1 = rl(a1, 0);
            float r0 = __builtin_amdgcn_rcpf(s0), r1 = __builtin_amdgcn_rcpf(s1);
            a0 *= r0; C0 -= __logf(r0);
            a1 *= r1; C1 -= __logf(r1);
        }
    }
    for (int u = t; u < len0; ++u) {
        STEP1(a0, __expf(ld0(u)));
        if ((u & 3) == 3) {
            float s = rl(a0, 0); float r = __builtin_amdgcn_rcpf(s);
            a0 *= r; C0 -= __logf(r);
        }
    }
    for (int u = t; u < len1; ++u) {
        STEP1(a1, __expf(ld1(u)));
        if ((u & 3) == 3) {
            float s = rl(a1, 0); float r = __builtin_amdgcn_rcpf(s);
            a1 *= r; C1 -= __logf(r);
        }
    }

    auto finish = [&](float a, float C) -> float {
        float aend = (act && a > 0.f) ? C + __logf(a) + trEnd : -1e30f;
        float mx = aend;
#pragma unroll
        for (int off = 32; off > 0; off >>= 1) mx = fmaxf(mx, __shfl_xor(mx, off, 64));
        float es = act ? __expf(aend - mx) : 0.f;
#pragma unroll
        for (int off = 32; off > 0; off >>= 1) es += __shfl_xor(es, off, 64);
        return mx + __logf(es);
    };
    float n0v = finish(a0, C0);
    float n1v = finish(a1, C1);

    if (lane == 0) {
        loss[b0] = g0 - n0v;
        loss[b1] = g1 - n1v;
    }
}

// ---------------------------------------------------------------------------
extern "C" void kernel_launch(void* const* d_in, const int* in_sizes, int n_in,
                              void* d_out, int out_size, void* d_ws, size_t ws_size,
                              hipStream_t stream) {
    const float* h        = (const float*)d_in[0];
    const int* token_nums = (const int*)d_in[2];
    const int* labels     = (const int*)d_in[3];
    const float* bio      = (const float*)d_in[4];
    const float* Wcat     = (const float*)d_in[5];
    const float* bcat     = (const float*)d_in[6];
    const float* Wcrf     = (const float*)d_in[7];
    const float* bcrf     = (const float*)d_in[8];
    const float* trans    = (const float*)d_in[9];

    float* out = (float*)d_out;
    unsigned short* attn  = (unsigned short*)d_out;  // 2MB scratch, overwritten by kCr

    const size_t ASW_BYTES = (size_t)128 * 48 * 16384;        // 96 MB
    const size_t P_BYTES   = (size_t)4 * NM * 48 * 4;         // 12.6 MB
    const size_t WSW_BYTES = (size_t)8 * 48 * 16384;          // 6 MB
    const size_t WT_BYTES  = (size_t)48 * 3072 * 2;           // 288 KB
    const bool fast = ws_size >= ASW_BYTES + P_BYTES + WSW_BYTES + WT_BYTES;

    hipLaunchKernelGGL(kA1, dim3(NM / 128), dim3(512), 0, stream, h, bio, attn);

    if (fast) {
        char*  Asw = (char*)d_ws;
        float* P   = (float*)((char*)d_ws + ASW_BYTES);
        char*  Wsw = (char*)d_ws + ASW_BYTES + P_BYTES;
        unsigned short* WT = (unsigned short*)((char*)d_ws + ASW_BYTES + P_BYTES + WSW_BYTES);

        hipLaunchKernelGGL(kW, dim3(8 * 48), dim3(256), 0, stream, Wcat, Wsw);
        hipLaunchKernelGGL(kW2, dim3(72), dim3(256), 0, stream, Wcrf, WT);
        hipLaunchKernelGGL(kA2f, dim3(NH / 128, NM / 128), dim3(256), 0, stream,
                           attn, bio, h, Asw);
        hipLaunchKernelGGL(kBf, dim3(256), dim3(512), 0, stream, Asw, Wsw, bcat, WT, P);
        hipLaunchKernelGGL(kCr, dim3(256), dim3(256), 0, stream, P, bcrf, out);
    } else {
        unsigned short* aware = (unsigned short*)d_ws;
        unsigned short* x2    = aware + (size_t)NM * NH;

        hipLaunchKernelGGL(kA2, dim3(NH / 128, NM / 128), dim3(256), 0, stream, attn, bio, aware);
        hipLaunchKernelGGL(kB, dim3((NH / 128) * (NM / 128)), dim3(256), 0, stream,
                           h, aware, Wcat, bcat, x2);
        hipLaunchKernelGGL(kC, dim3(NM / 128), dim3(256), 0, stream, x2, Wcrf, bcrf, out);
    }

    hipLaunchKernelGGL(kD, dim3(NB / 2), dim3(64), 0, stream, out, labels, token_nums, trans,
                       out + (size_t)NM * NLP);
}

// Round 13
// 244.749 us; speedup vs baseline: 1.3483x; 1.3483x over previous
//
#include <hip/hip_runtime.h>
#include <hip/hip_bf16.h>
#include <math.h>

#define NB 32
#define NS 512
#define NH 1024
#define NT 37
#define NLP 39
#define NM (NB*NS)   // 16384

typedef __attribute__((ext_vector_type(8))) short bf16x8;
typedef __attribute__((ext_vector_type(4))) float f32x4;

__device__ __forceinline__ float bf2f(unsigned int u) {
    unsigned int x = u << 16;
    float f;
    __builtin_memcpy(&f, &x, 4);
    return f;
}
__device__ __forceinline__ unsigned short f2bf(float f) {
    __hip_bfloat16 hb = __float2bfloat16(f);
    unsigned short u;
    __builtin_memcpy(&u, &hb, 2);
    return u;
}
__device__ __forceinline__ unsigned int pk2(float lo, float hi) {
    return ((unsigned int)f2bf(hi) << 16) | (unsigned int)f2bf(lo);
}
// bijective XOR swizzle for [row][64B] bf16 LDS tiles
__device__ __forceinline__ int SW64(int b)  { return b ^ ((b >> 2) & 0x70); }
// tile swizzle for [128/256 row][64 k] bf16 tiles (row stride 128B)
__device__ __forceinline__ int TSW(int row, int kcolByte) {
    return (row * 128 + kcolByte) ^ ((row & 7) << 4);
}
__device__ __forceinline__ float rl(float x, int l) {
    return __int_as_float(__builtin_amdgcn_readlane(__float_as_int(x), l));
}
__device__ __forceinline__ void gld16(const void* g, void* l) {
    __builtin_amdgcn_global_load_lds((const __attribute__((address_space(1))) void*)g,
                                     (__attribute__((address_space(3))) void*)l, 16, 0, 0);
}
#define VMW(N) asm volatile("s_waitcnt vmcnt(" #N ")" ::: "memory")
#define BARR() do { __builtin_amdgcn_s_barrier(); __builtin_amdgcn_sched_barrier(0); } while (0)

// ---------------------------------------------------------------------------
// Kernel A1 (v2): scores = h@bio^T /32 -> softmax -> attn (bf16 [NM][64]).
// ---------------------------------------------------------------------------
__global__ __launch_bounds__(512) void kA1(const float* __restrict__ h,
                                           const float* __restrict__ bio,
                                           unsigned short* __restrict__ attn) {
    __shared__ __align__(16) char Bl[48 * 2048];   // 96KB: [t][1024k] bf16, ^(t&7)<<4

    const int tid  = threadIdx.x;
    const int lane = tid & 63;
    const int wid  = tid >> 6;
    const int lr   = lane & 15;
    const int lk   = lane >> 4;
    const int m0   = blockIdx.x * 128;

    for (int idx = tid; idx < 37 * 256; idx += 512) {
        int t = idx >> 8, k4 = idx & 255;
        float4 v = *(const float4*)&bio[(size_t)t * NH + k4 * 4];
        int byte = (t * 2048 + k4 * 8) ^ ((t & 7) << 4);
        *(uint2*)(Bl + byte) = make_uint2(pk2(v.x, v.y), pk2(v.z, v.w));
    }
    for (int idx = tid; idx < 11 * 256; idx += 512) {
        int t = 37 + (idx >> 8), k4 = idx & 255;
        int byte = (t * 2048 + k4 * 8) ^ ((t & 7) << 4);
        *(uint2*)(Bl + byte) = make_uint2(0, 0);
    }
    __syncthreads();

    const int arow = m0 + wid * 16 + lr;
    const float* hp = h + (size_t)arow * NH + lk * 8;

    f32x4 sacc[3];
#pragma unroll
    for (int j = 0; j < 3; ++j) sacc[j] = (f32x4){0.f, 0.f, 0.f, 0.f};

    float4 p0 = *(const float4*)(hp);
    float4 p1 = *(const float4*)(hp + 4);
    for (int kt = 0; kt < NH; kt += 32) {
        float4 c0 = p0, c1 = p1;
        if (kt + 32 < NH) {
            p0 = *(const float4*)(hp + kt + 32);
            p1 = *(const float4*)(hp + kt + 36);
        }
        union { unsigned int u[4]; bf16x8 v; } af;
        af.u[0] = pk2(c0.x, c0.y); af.u[1] = pk2(c0.z, c0.w);
        af.u[2] = pk2(c1.x, c1.y); af.u[3] = pk2(c1.z, c1.w);
#pragma unroll
        for (int nf = 0; nf < 3; ++nf) {
            int t = nf * 16 + lr;
            int byte = (t * 2048 + (kt + lk * 8) * 2) ^ ((t & 7) << 4);
            bf16x8 bf = *(const bf16x8*)(Bl + byte);
            sacc[nf] = __builtin_amdgcn_mfma_f32_16x16x32_bf16(af.v, bf, sacc[nf], 0, 0, 0);
        }
    }

#pragma unroll
    for (int r = 0; r < 4; ++r) {
        const int orow = wid * 16 + lk * 4 + r;
        float s0 = sacc[0][r] * 0.03125f;
        float s1 = sacc[1][r] * 0.03125f;
        float s2 = sacc[2][r] * 0.03125f;
        const bool v2 = (lr < 5);
        float mx = fmaxf(fmaxf(s0, s1), v2 ? s2 : -1e30f);
#pragma unroll
        for (int d = 1; d < 16; d <<= 1) mx = fmaxf(mx, __shfl_xor(mx, d, 64));
        float e0 = __expf(s0 - mx), e1 = __expf(s1 - mx);
        float e2 = v2 ? __expf(s2 - mx) : 0.f;
        float sm = e0 + e1 + e2;
#pragma unroll
        for (int d = 1; d < 16; d <<= 1) sm += __shfl_xor(sm, d, 64);
        float inv = 1.f / sm;
        size_t g = (size_t)(m0 + orow) * 64;
        attn[g + lr]      = f2bf(e0 * inv);
        attn[g + 16 + lr] = f2bf(e1 * inv);
        attn[g + 32 + lr] = f2bf(e2 * inv);
        attn[g + 48 + lr] = 0;
    }
}

// ---------------------------------------------------------------------------
// Kernel A2 (fallback): aware = attn @ bio, plain bf16 row-major out.
// ---------------------------------------------------------------------------
__global__ __launch_bounds__(256) void kA2(const unsigned short* __restrict__ attn,
                                           const float* __restrict__ bio,
                                           unsigned short* __restrict__ aware) {
    __shared__ __align__(16) char Bsl[128 * 64];

    const int tid  = threadIdx.x;
    const int lane = tid & 63;
    const int wid  = tid >> 6;
    const int wm   = (wid >> 1) * 64;
    const int wn   = (wid & 1) * 64;
    const int lr   = lane & 15;
    const int lk   = lane >> 4;
    const int n0   = blockIdx.x * 128;
    const int m0   = blockIdx.y * 128;

    const int bn = tid & 127;
    const int bq = (tid >> 7) * 16;

    f32x4 acc[4][4];
#pragma unroll
    for (int i = 0; i < 4; ++i)
#pragma unroll
        for (int j = 0; j < 4; ++j) acc[i][j] = (f32x4){0.f, 0.f, 0.f, 0.f};

#pragma unroll
    for (int ks = 0; ks < 2; ++ks) {
        unsigned int p[8];
#pragma unroll
        for (int i = 0; i < 8; ++i) {
            int t0 = ks*32 + bq + 2*i;
            float lo = (t0     < NT) ? bio[(size_t)t0 * NH + n0 + bn]       : 0.f;
            float hi = (t0 + 1 < NT) ? bio[(size_t)(t0+1) * NH + n0 + bn]   : 0.f;
            p[i] = pk2(lo, hi);
        }
        __syncthreads();
        *(int4*)(Bsl + SW64(bn*64 + bq*2))      = make_int4(p[0], p[1], p[2], p[3]);
        *(int4*)(Bsl + SW64(bn*64 + bq*2 + 16)) = make_int4(p[4], p[5], p[6], p[7]);
        __syncthreads();

        bf16x8 af[4];
#pragma unroll
        for (int mf = 0; mf < 4; ++mf)
            af[mf] = *(const bf16x8*)(attn + (size_t)(m0 + wm + mf*16 + lr) * 64 + ks*32 + lk*8);
#pragma unroll
        for (int nf = 0; nf < 4; ++nf) {
            bf16x8 bb = *(const bf16x8*)(Bsl + SW64((wn + nf*16 + lr)*64 + lk*16));
#pragma unroll
            for (int mf = 0; mf < 4; ++mf)
                acc[mf][nf] = __builtin_amdgcn_mfma_f32_16x16x32_bf16(af[mf], bb, acc[mf][nf], 0, 0, 0);
        }
    }

#pragma unroll
    for (int mf = 0; mf < 4; ++mf)
#pragma unroll
        for (int nf = 0; nf < 4; ++nf)
#pragma unroll
            for (int r = 0; r < 4; ++r) {
                size_t row = (size_t)(m0 + wm + mf*16 + lk*4 + r);
                aware[row * NH + n0 + wn + nf*16 + lr] = f2bf(acc[mf][nf][r]);
            }
}

// ---------------------------------------------------------------------------
// Kernel A2f (fast): computes aware chunk AND writes the full concat-A
// [h | aware | h*aware] in bf16, tile-major (128x64 tiles) with TSW swizzle.
// ---------------------------------------------------------------------------
__global__ __launch_bounds__(256) void kA2f(const unsigned short* __restrict__ attn,
                                            const float* __restrict__ bio,
                                            const float* __restrict__ h,
                                            char* __restrict__ Asw) {
    __shared__ __align__(16) char Bsl[128 * 64];
    __shared__ __align__(16) unsigned short awL[128 * 128];  // 32KB aware chunk

    const int tid  = threadIdx.x;
    const int lane = tid & 63;
    const int wid  = tid >> 6;
    const int wm   = (wid >> 1) * 64;
    const int wn   = (wid & 1) * 64;
    const int lr   = lane & 15;
    const int lk   = lane >> 4;
    const int n0   = blockIdx.x * 128;
    const int m0   = blockIdx.y * 128;
    const int tm   = blockIdx.y;

    const int bn = tid & 127;
    const int bq = (tid >> 7) * 16;

    f32x4 acc[4][4];
#pragma unroll
    for (int i = 0; i < 4; ++i)
#pragma unroll
        for (int j = 0; j < 4; ++j) acc[i][j] = (f32x4){0.f, 0.f, 0.f, 0.f};

#pragma unroll
    for (int ks = 0; ks < 2; ++ks) {
        unsigned int p[8];
#pragma unroll
        for (int i = 0; i < 8; ++i) {
            int t0 = ks*32 + bq + 2*i;
            float lo = (t0     < NT) ? bio[(size_t)t0 * NH + n0 + bn]       : 0.f;
            float hi = (t0 + 1 < NT) ? bio[(size_t)(t0+1) * NH + n0 + bn]   : 0.f;
            p[i] = pk2(lo, hi);
        }
        __syncthreads();
        *(int4*)(Bsl + SW64(bn*64 + bq*2))      = make_int4(p[0], p[1], p[2], p[3]);
        *(int4*)(Bsl + SW64(bn*64 + bq*2 + 16)) = make_int4(p[4], p[5], p[6], p[7]);
        __syncthreads();

        bf16x8 af[4];
#pragma unroll
        for (int mf = 0; mf < 4; ++mf)
            af[mf] = *(const bf16x8*)(attn + (size_t)(m0 + wm + mf*16 + lr) * 64 + ks*32 + lk*8);
#pragma unroll
        for (int nf = 0; nf < 4; ++nf) {
            bf16x8 bb = *(const bf16x8*)(Bsl + SW64((wn + nf*16 + lr)*64 + lk*16));
#pragma unroll
            for (int mf = 0; mf < 4; ++mf)
                acc[mf][nf] = __builtin_amdgcn_mfma_f32_16x16x32_bf16(af[mf], bb, acc[mf][nf], 0, 0, 0);
        }
    }

#pragma unroll
    for (int mf = 0; mf < 4; ++mf)
#pragma unroll
        for (int nf = 0; nf < 4; ++nf)
#pragma unroll
            for (int r = 0; r < 4; ++r)
                awL[(wm + mf*16 + lk*4 + r) * 128 + wn + nf*16 + lr] = f2bf(acc[mf][nf][r]);
    __syncthreads();

    // region 1 (aware)
#pragma unroll
    for (int i = 0; i < 8; ++i) {
        int lin = tid + i * 256;
        int row = lin >> 4, kg = lin & 15;
        uint4 v = *(const uint4*)&awL[row * 128 + kg * 8];
        int kglob = 1024 + n0 + kg * 8;
        size_t tbase = ((size_t)tm * 48 + (kglob >> 6)) * 16384;
        *(uint4*)(Asw + tbase + TSW(row, (kglob & 63) * 2)) = v;
    }
    // regions 0 (h) and 2 (h*aware)
#pragma unroll
    for (int i = 0; i < 8; ++i) {
        int lin = tid + i * 256;
        int row = lin >> 4, kg = lin & 15;
        const float4* hp = (const float4*)&h[(size_t)(m0 + row) * NH + n0 + kg * 8];
        float4 ha = hp[0], hb = hp[1];
        float hv[8] = {ha.x, ha.y, ha.z, ha.w, hb.x, hb.y, hb.z, hb.w};
        uint4 awv = *(const uint4*)&awL[row * 128 + kg * 8];
        unsigned int awu[4] = {awv.x, awv.y, awv.z, awv.w};
        unsigned int p0[4], p2[4];
#pragma unroll
        for (int j = 0; j < 4; ++j) {
            p0[j] = pk2(hv[2*j], hv[2*j+1]);
            float lo = hv[2*j]   * bf2f(awu[j] & 0xffffu);
            float hi = hv[2*j+1] * bf2f(awu[j] >> 16);
            p2[j] = pk2(lo, hi);
        }
        int k0g = n0 + kg * 8;
        size_t tb0 = ((size_t)tm * 48 + (k0g >> 6)) * 16384;
        *(uint4*)(Asw + tb0 + TSW(row, (k0g & 63) * 2)) = make_uint4(p0[0], p0[1], p0[2], p0[3]);
        int k2g = 2048 + n0 + kg * 8;
        size_t tb2 = ((size_t)tm * 48 + (k2g >> 6)) * 16384;
        *(uint4*)(Asw + tb2 + TSW(row, (k2g & 63) * 2)) = make_uint4(p2[0], p2[1], p2[2], p2[3]);
    }
}

// ---------------------------------------------------------------------------
// Kernel W: WbT swizzled tiles: W^T[n][k] bf16, tile (tn,tk) = [128 n][64 k].
// ---------------------------------------------------------------------------
__global__ __launch_bounds__(256) void kW(const float* __restrict__ Wcat,
                                          char* __restrict__ Wsw) {
    __shared__ unsigned short wt[64 * 128];

    const int tid  = threadIdx.x;
    const int tile = blockIdx.x;
    const int tn   = tile / 48;
    const int tk   = tile - tn * 48;
    const int n00  = tn * 128;
    const int k0   = tk * 64;

#pragma unroll
    for (int i = 0; i < 8; ++i) {
        int lin = tid + i * 256;
        int kk = lin >> 5, ng = lin & 31;
        float4 v = *(const float4*)&Wcat[(size_t)(k0 + kk) * NH + n00 + ng * 4];
        unsigned int lo = pk2(v.x, v.y), hi = pk2(v.z, v.w);
        *(uint2*)&wt[kk * 128 + ng * 4] = make_uint2(lo, hi);
    }
    __syncthreads();
#pragma unroll
    for (int i = 0; i < 4; ++i) {
        int lin = tid + i * 256;
        int rn = lin >> 3, kg = lin & 7;
        unsigned short t8[8];
#pragma unroll
        for (int j = 0; j < 8; ++j) t8[j] = wt[(kg * 8 + j) * 128 + rn];
        uint4 v = *(const uint4*)t8;
        *(uint4*)(Wsw + (size_t)tile * 16384 + TSW(rn, kg * 16)) = v;
    }
}

// ---------------------------------------------------------------------------
// Kernel W2: prepack Wcrf^T as bf16 [48][3072], rows t>=37 zeroed.
// ---------------------------------------------------------------------------
__global__ __launch_bounds__(256) void kW2(const float* __restrict__ Wcrf,
                                           unsigned short* __restrict__ WT) {
    const int idx = blockIdx.x * 256 + threadIdx.x;   // 48*384 = 18432
    if (idx >= 48 * 384) return;
    const int t = idx / 384, kg = idx - t * 384;
    unsigned short v[8];
#pragma unroll
    for (int e = 0; e < 8; ++e) {
        int k = kg * 8 + e;
        v[e] = (t < NT) ? f2bf(Wcrf[(size_t)k * NT + t]) : (unsigned short)0;
    }
    uint4 w;
    __builtin_memcpy(&w, v, 16);
    *(uint4*)(WT + (size_t)t * 3072 + kg * 8) = w;
}

// ---------------------------------------------------------------------------
// Kernel Bf (fast): 256x256 tile bf16 GEMM, BK=64, 8 waves, counted-vmcnt
// 4-phase schedule + fused kC epilogue (prepacked Wcrf^T). (round-11 proven)
// ---------------------------------------------------------------------------
__global__ __launch_bounds__(512, 2) void kBf(const char* __restrict__ Asw,
                                              const char* __restrict__ Wsw,
                                              const float* __restrict__ bcat,
                                              const unsigned short* __restrict__ WT,
                                              float* __restrict__ P) {
    __shared__ __align__(16) char lds[131072];  // A: buf*32768+h*16384; B at +65536

    const int tid  = threadIdx.x;
    const int lane = tid & 63;
    const int wid  = tid >> 6;
    const int widm = wid >> 2;       // 0..1
    const int widn = wid & 3;        // 0..3
    const int lr   = lane & 15;
    const int lk   = lane >> 4;

    const int id   = blockIdx.x;     // 256 blocks
    const int xcd  = id & 7;
    const int slot = id >> 3;        // 0..31
    const int Mt   = xcd * 8 + (slot >> 2);
    const int Nt   = slot & 3;
    const int m0   = Mt * 256, n0 = Nt * 256;
    const int soff = tid * 16;

    f32x4 acc00[4][2], acc01[4][2], acc10[4][2], acc11[4][2];
#pragma unroll
    for (int i = 0; i < 4; ++i)
#pragma unroll
        for (int j = 0; j < 2; ++j) {
            acc00[i][j] = (f32x4){0.f,0.f,0.f,0.f};
            acc01[i][j] = (f32x4){0.f,0.f,0.f,0.f};
            acc10[i][j] = (f32x4){0.f,0.f,0.f,0.f};
            acc11[i][j] = (f32x4){0.f,0.f,0.f,0.f};
        }

    auto stageHalf = [&](int T, int ph) {
        const bool isA = (ph == 0) || (ph == 3);
        const int  h   = isA ? (ph == 3 ? 1 : 0) : (ph - 1);
        const char* src = isA
            ? Asw + ((size_t)((2*Mt + h) * 48 + T)) * 16384
            : Wsw + ((size_t)((2*Nt + h) * 48 + T)) * 16384;
        char* dst = lds + (isA ? 0 : 65536) + (T & 1) * 32768 + h * 16384;
        gld16(src + soff,        dst + soff);
        gld16(src + soff + 8192, dst + soff + 8192);
    };
    auto loadA = [&](bf16x8 (&af)[4][2], int q, int half) {
        const char* base = lds + q * 32768 + half * 16384;
#pragma unroll
        for (int i = 0; i < 4; ++i) {
            int row = widm * 64 + i * 16 + lr;
#pragma unroll
            for (int kk = 0; kk < 2; ++kk)
                af[i][kk] = *(const bf16x8*)(base + TSW(row, kk * 64 + lk * 16));
        }
    };
    auto loadB = [&](bf16x8 (&bfr)[2][2], int q, int half) {
        const char* base = lds + 65536 + q * 32768 + half * 16384;
#pragma unroll
        for (int j = 0; j < 2; ++j) {
            int col = widn * 32 + j * 16 + lr;
#pragma unroll
            for (int kk = 0; kk < 2; ++kk)
                bfr[j][kk] = *(const bf16x8*)(base + TSW(col, kk * 64 + lk * 16));
        }
    };
    auto mma = [&](f32x4 (&ac)[4][2], bf16x8 (&af)[4][2], bf16x8 (&bfr)[2][2]) {
        __builtin_amdgcn_s_setprio(1);
#pragma unroll
        for (int kk = 0; kk < 2; ++kk)
#pragma unroll
            for (int i = 0; i < 4; ++i)
#pragma unroll
                for (int j = 0; j < 2; ++j)
                    ac[i][j] = __builtin_amdgcn_mfma_f32_16x16x32_bf16(
                        af[i][kk], bfr[j][kk], ac[i][j], 0, 0, 0);
        __builtin_amdgcn_s_setprio(0);
    };

    stageHalf(0, 0); stageHalf(0, 1); stageHalf(0, 2); stageHalf(0, 3);
    VMW(0);
    BARR();

    for (int T = 0; T < 47; ++T) {
        const int q = T & 1;
        bf16x8 af0[4][2], af1[4][2], bf0[2][2], bf1[2][2];
        stageHalf(T + 1, 0);
        VMW(6);
        BARR();
        loadA(af0, q, 0); loadB(bf0, q, 0);
        mma(acc00, af0, bf0);
        stageHalf(T + 1, 1);
        VMW(6);
        BARR();
        loadB(bf1, q, 1);
        mma(acc01, af0, bf1);
        stageHalf(T + 1, 2);
        VMW(6);
        BARR();
        loadA(af1, q, 1);
        mma(acc10, af1, bf0);
        stageHalf(T + 1, 3);
        BARR();
        mma(acc11, af1, bf1);
    }
    {   // T = 47 (buf 1), tail waits 4/2/0
        const int q = 1;
        bf16x8 af0[4][2], af1[4][2], bf0[2][2], bf1[2][2];
        VMW(4);
        BARR();
        loadA(af0, q, 0); loadB(bf0, q, 0);
        mma(acc00, af0, bf0);
        VMW(2);
        BARR();
        loadB(bf1, q, 1);
        mma(acc01, af0, bf1);
        VMW(0);
        BARR();
        loadA(af1, q, 1);
        mma(acc10, af1, bf0);
        BARR();
        mma(acc11, af1, bf1);
    }

    // ---------------- fused kC epilogue ----------------
    __syncthreads();
    auto stashQ = [&](f32x4 (&ac)[4][2], int a, int b) {
#pragma unroll
        for (int j = 0; j < 2; ++j) {
            const int lcol = b * 128 + widn * 32 + j * 16 + lr;
            const int kc = lcol >> 6, kk = lcol & 63;
            const float bc = bcat[n0 + lcol];
#pragma unroll
            for (int i = 0; i < 4; ++i)
#pragma unroll
                for (int r = 0; r < 4; ++r) {
                    int lrow = a * 128 + widm * 64 + i * 16 + lk * 4 + r;
                    float x = ac[i][j][r] + bc;
                    float g = 0.5f * x * (1.0f + erff(x * 0.70710678118654752f));
                    *(unsigned short*)(lds + kc * 32768 + TSW(lrow, kk * 2)) = f2bf(g);
                }
        }
    };
    stashQ(acc00, 0, 0); stashQ(acc01, 0, 1); stashQ(acc10, 1, 0); stashQ(acc11, 1, 1);
    __syncthreads();

    bf16x8 wfrag[3][8];
#pragma unroll
    for (int tt = 0; tt < 3; ++tt) {
        const int t = tt * 16 + lr;
#pragma unroll
        for (int ks = 0; ks < 8; ++ks)
            wfrag[tt][ks] = *(const bf16x8*)(WT + (size_t)t * 3072 + n0 + ks * 32 + lk * 8);
    }

    f32x4 pacc[2][3];
#pragma unroll
    for (int i = 0; i < 2; ++i)
#pragma unroll
        for (int j = 0; j < 3; ++j) pacc[i][j] = (f32x4){0.f, 0.f, 0.f, 0.f};
#pragma unroll
    for (int rt2 = 0; rt2 < 2; ++rt2) {
        const int lrow = wid * 32 + rt2 * 16 + lr;
#pragma unroll
        for (int ks = 0; ks < 8; ++ks) {
            const int kc = ks >> 1, kh = ks & 1;
            bf16x8 af = *(const bf16x8*)(lds + kc * 32768 + TSW(lrow, kh * 64 + lk * 16));
#pragma unroll
            for (int tt = 0; tt < 3; ++tt)
                pacc[rt2][tt] = __builtin_amdgcn_mfma_f32_16x16x32_bf16(
                    af, wfrag[tt][ks], pacc[rt2][tt], 0, 0, 0);
        }
    }

    float* Pb = P + (size_t)Nt * NM * 48;
#pragma unroll
    for (int rt2 = 0; rt2 < 2; ++rt2)
#pragma unroll
        for (int tt = 0; tt < 3; ++tt)
#pragma unroll
            for (int r = 0; r < 4; ++r) {
                int row = Mt * 256 + wid * 32 + rt2 * 16 + lk * 4 + r;
                Pb[(size_t)row * 48 + tt * 16 + lr] = pacc[rt2][tt][r];
            }
}

// ---------------------------------------------------------------------------
// Kernel Cr: out = sum_Nt P[Nt] + b_crf, pads -10000.
// ---------------------------------------------------------------------------
__global__ __launch_bounds__(256) void kCr(const float* __restrict__ P,
                                           const float* __restrict__ bcrf,
                                           float* __restrict__ out) {
    const int g = blockIdx.x * 256 + threadIdx.x;
    const size_t STRIDE = (size_t)NM * 48;
#pragma unroll
    for (int s = 0; s < 12; ++s) {
        int flat = g * 12 + s;
        int row = flat / 48, t = flat - row * 48;
        float v = P[flat] + P[STRIDE + flat] + P[2*STRIDE + flat] + P[3*STRIDE + flat];
        if (t < NT)       out[(size_t)row * NLP + t] = v + bcrf[t];
        else if (t < NLP) out[(size_t)row * NLP + t] = -10000.0f;
    }
}

// ---------------------------------------------------------------------------
// Kernel Dm: segment matrix scan. Block = (batch b, segment s), ONE wave.
// Computes M_s = prod_{t=t1-1..t0} D_t*T (48x48, exp domain) via MFMA:
// per step M' = rowscale_el( T @ M ). M double-buffered col-major bf16 in
// LDS (rows 48-63 zeroed once); T bf16 fragments static in regs; el table
// precomputed. Rescale by M[0][0] every 4 steps, log-scale in Cacc.
// Output: Pm[b][s] = M_s (fp32 row-major 48x48), Pc[b][s] = Cacc.
// ---------------------------------------------------------------------------
__global__ __launch_bounds__(64) void kDm(const float* __restrict__ scores,
                                          const int* __restrict__ lens,
                                          const float* __restrict__ trans,
                                          float* __restrict__ Pm,
                                          float* __restrict__ Pc) {
    __shared__ float el_all[64 * 64];          // 16KB [step][row]
    __shared__ __align__(16) char Mb[2 * 6144]; // col-major bf16 [col][k0..63], swz

    const int lane = threadIdx.x;
    const int b    = blockIdx.x >> 3;
    const int s    = blockIdx.x & 7;
    const int lr   = lane & 15;
    const int lk   = lane >> 4;
    const int len  = lens[b];
    const int t0   = s * 64;
    const int nsteps = (len > t0) ? ((len - t0 < 64) ? (len - t0) : 64) : 0;
    const float* sb = scores + (size_t)b * NS * NLP;
    float* Pg = Pm + (size_t)(b * 8 + s) * 2304;

    if (nsteps == 0) {
        // M = I
        for (int j = 0; j < 36; ++j) {
            int flat = j * 64 + lane;          // 0..2303
            Pg[flat] = 0.f;
        }
        if (lane < 48) Pg[lane * 48 + lane] = (lane < NLP) ? 1.f : 1.f;
        if (lane == 0) Pc[b * 8 + s] = 0.f;
        return;
    }

    // el table: el_all[i][row] = exp(logit[t0+i][row]) (rows>=39 -> 0)
    for (int i = 0; i < 64; ++i) {
        float v = 0.f;
        if (i < nsteps && lane < NLP) v = __expf(sb[(size_t)(t0 + i) * NLP + lane]);
        el_all[i * 64 + lane] = v;
    }

    // T fragments: T[row][f] = exp(trans[row][f]), zero-padded
    bf16x8 Tf[3][2];
#pragma unroll
    for (int tt = 0; tt < 3; ++tt)
#pragma unroll
        for (int ks = 0; ks < 2; ++ks) {
            const int row = tt * 16 + lr;
            unsigned int u[4];
#pragma unroll
            for (int e2 = 0; e2 < 4; ++e2) {
                int f0 = ks * 32 + lk * 8 + 2 * e2;
                float lo = (row < NLP && f0     < NLP) ? __expf(trans[row * NLP + f0])     : 0.f;
                float hi = (row < NLP && f0 + 1 < NLP) ? __expf(trans[row * NLP + f0 + 1]) : 0.f;
                u[e2] = pk2(lo, hi);
            }
            union { unsigned int uu[4]; bf16x8 v; } cv;
            cv.uu[0]=u[0]; cv.uu[1]=u[1]; cv.uu[2]=u[2]; cv.uu[3]=u[3];
            Tf[tt][ks] = cv.v;
        }

    // init M buffers: zero both fully, set I in buf 0
    for (int j = 0; j < 48; ++j)               // 2*6144B / 64 lanes / 4B = 48
        *(unsigned int*)(Mb + j * 256 + lane * 4) = 0;
    if (lane < 48) {
        int byte = (lane * 128 + lane * 2) ^ ((lane & 7) << 4);
        *(unsigned short*)(Mb + byte) = f2bf(1.0f);
    }

    float Cacc = 0.f;

    for (int i = 0; i < nsteps; ++i) {
        const int q = i & 1;
        const char* Mr = Mb + q * 6144;

        // B fragments: M[k][col], col = ct*16+lr, k = ks*32+lk*8..+7
        bf16x8 Bf[3][2];
#pragma unroll
        for (int ct = 0; ct < 3; ++ct) {
#pragma unroll
            for (int ks = 0; ks < 2; ++ks) {
                int col = ct * 16 + lr;
                int byte = (col * 128 + (ks * 32 + lk * 8) * 2) ^ ((col & 7) << 4);
                Bf[ct][ks] = *(const bf16x8*)(Mr + byte);
            }
        }
        // el rows for this lane's C rows
        f32x4 el4[3];
#pragma unroll
        for (int tt = 0; tt < 3; ++tt)
            el4[tt] = *(const f32x4*)&el_all[i * 64 + tt * 16 + lk * 4];

        // C = T @ M
        f32x4 c[3][3];
#pragma unroll
        for (int tt = 0; tt < 3; ++tt)
#pragma unroll
            for (int ct = 0; ct < 3; ++ct) {
                c[tt][ct] = __builtin_amdgcn_mfma_f32_16x16x32_bf16(
                    Tf[tt][0], Bf[ct][0], (f32x4){0.f,0.f,0.f,0.f}, 0, 0, 0);
                c[tt][ct] = __builtin_amdgcn_mfma_f32_16x16x32_bf16(
                    Tf[tt][1], Bf[ct][1], c[tt][ct], 0, 0, 0);
            }
        // row scale by el
#pragma unroll
        for (int tt = 0; tt < 3; ++tt)
#pragma unroll
            for (int ct = 0; ct < 3; ++ct)
#pragma unroll
                for (int r = 0; r < 4; ++r)
                    c[tt][ct][r] *= el4[tt][r];

        // periodic rescale by M'[0][0] (lane 0, tile(0,0), reg 0; > 0)
        if ((i & 3) == 3) {
            float sv = rl(c[0][0][0], 0);
            float rr = __builtin_amdgcn_rcpf(sv);
#pragma unroll
            for (int tt = 0; tt < 3; ++tt)
#pragma unroll
                for (int ct = 0; ct < 3; ++ct)
#pragma unroll
                    for (int r = 0; r < 4; ++r) c[tt][ct][r] *= rr;
            Cacc -= __logf(rr);
        }

        if (i == nsteps - 1) {
            // write fp32 row-major to global
#pragma unroll
            for (int tt = 0; tt < 3; ++tt)
#pragma unroll
                for (int ct = 0; ct < 3; ++ct)
#pragma unroll
                    for (int r = 0; r < 4; ++r) {
                        int row = tt * 16 + lk * 4 + r;
                        int col = ct * 16 + lr;
                        Pg[row * 48 + col] = c[tt][ct][r];
                    }
        } else {
            // pack to bf16, store to other buffer
            char* Mw = Mb + (q ^ 1) * 6144;
#pragma unroll
            for (int tt = 0; tt < 3; ++tt)
#pragma unroll
                for (int ct = 0; ct < 3; ++ct) {
                    int col = ct * 16 + lr;
                    int k   = tt * 16 + lk * 4;
                    int byte = (col * 128 + k * 2) ^ ((col & 7) << 4);
                    *(uint2*)(Mw + byte) = make_uint2(pk2(c[tt][ct][0], c[tt][ct][1]),
                                                      pk2(c[tt][ct][2], c[tt][ct][3]));
                }
        }
    }

    if (lane == 0) Pc[b * 8 + s] = Cacc;
}

// ---------------------------------------------------------------------------
// Kernel Dc: combine. Block = batch (256 thr): 4-wave gold path, then wave 0
// chains v <- M_s v from v = e_START, rescaling each hop; logsumexp finish.
// ---------------------------------------------------------------------------
__global__ __launch_bounds__(256) void kDc(const float* __restrict__ scores,
                                           const int* __restrict__ labels,
                                           const int* __restrict__ lens,
                                           const float* __restrict__ trans,
                                           const float* __restrict__ Pm,
                                           const float* __restrict__ Pc,
                                           float* __restrict__ loss) {
    __shared__ float trL[39 * 41];
    __shared__ float gred[4];

    const int b    = blockIdx.x;
    const int tid  = threadIdx.x;
    const int lane = tid & 63;
    const int wid  = tid >> 6;
    const int len  = lens[b];
    const float* sb = scores + (size_t)b * NS * NLP;

    for (int idx = tid; idx < 39 * 39; idx += 256) {
        int to = idx / 39, f = idx - to * 39;
        trL[to * 41 + f] = trans[idx];
    }
    __syncthreads();

    // gold path
    float g = 0.0f;
    for (int t = tid; t < len; t += 256) g += sb[(size_t)t * NLP + labels[b * NS + t]];
    for (int i = tid; i <= len; i += 256) {
        int frm = (i == 0) ? 37 : labels[b * NS + i - 1];
        int to  = (i == len) ? 38 : labels[b * NS + i];
        g += trL[to * 41 + frm];
    }
#pragma unroll
    for (int off = 32; off > 0; off >>= 1) g += __shfl_xor(g, off, 64);
    if (lane == 0) gred[wid] = g;
    __syncthreads();

    if (wid != 0) return;

    const float gold = (gred[0] + gred[1]) + (gred[2] + gred[3]);
    const bool act48 = (lane < 48);

    // v = M_0[:,37]  (exp(alpha after step 63))
    const float* P0 = Pm + (size_t)b * 8 * 2304;
    float v = act48 ? P0[lane * 48 + 37] : 0.f;
    float C = Pc[b * 8];

    for (int s = 1; s < 8; ++s) {
        // broadcast v (f = 0..39; 37..39 are 0 but harmless)
        float as_[40];
#pragma unroll
        for (int f = 0; f < 40; ++f) as_[f] = rl(v, f);
        __builtin_amdgcn_sched_barrier(0);
        const float* Ps = Pm + (size_t)(b * 8 + s) * 2304;
        float c = 0.f;
        if (act48) {
            const float4* rowp = (const float4*)(Ps + lane * 48);
#pragma unroll
            for (int q = 0; q < 10; ++q) {
                float4 rv = rowp[q];
                c = fmaf(rv.x, as_[q*4+0], c);
                c = fmaf(rv.y, as_[q*4+1], c);
                c = fmaf(rv.z, as_[q*4+2], c);
                c = fmaf(rv.w, as_[q*4+3], c);
            }
        }
        // rescale by c[0] (> 0)
        float sv = rl(c, 0);
        float rr = __builtin_amdgcn_rcpf(sv);
        v = c * rr;
        C -= __logf(rr);
        C += Pc[b * 8 + s];
    }

    const float trEnd = (lane < NLP) ? trL[38 * 41 + lane] : 0.f;
    float aend = (lane < NLP && v > 0.f) ? C + __logf(v) + trEnd : -1e30f;
    float mx = aend;
#pragma unroll
    for (int off = 32; off > 0; off >>= 1) mx = fmaxf(mx, __shfl_xor(mx, off, 64));
    float es = (lane < NLP) ? __expf(aend - mx) : 0.f;
#pragma unroll
    for (int off = 32; off > 0; off >>= 1) es += __shfl_xor(es, off, 64);
    float norm = mx + __logf(es);

    if (lane == 0) loss[b] = gold - norm;
}

// ---------------------------------------------------------------------------
// Kernel B (fallback): reg-staged mixed GEMM (round-4 version).
// ---------------------------------------------------------------------------
__global__ __launch_bounds__(256) void kB(const float* __restrict__ h,
                                          const unsigned short* __restrict__ aware,
                                          const float* __restrict__ Wcat,
                                          const float* __restrict__ bcat,
                                          unsigned short* __restrict__ x2) {
    __shared__ __align__(16) char lds[16384];
    char* Asl = lds;
    char* Bsl = lds + 8192;

    const int tid  = threadIdx.x;
    const int lane = tid & 63;
    const int wid  = tid >> 6;
    const int wm   = (wid >> 1) * 64;
    const int wn   = (wid & 1) * 64;
    const int lr   = lane & 15;
    const int lk   = lane >> 4;

    const int id   = blockIdx.x;
    const int xcd  = id & 7;
    const int slot = id >> 3;
    const int m0   = (xcd * 16 + (slot >> 3)) * 128;
    const int n0   = (slot & 7) * 128;

    const int am = tid >> 1;
    const int ak = (tid & 1) * 16;
    const int bn = tid & 127;
    const int bk = (tid >> 7) * 16;

    f32x4 acc[4][4];
#pragma unroll
    for (int i = 0; i < 4; ++i)
#pragma unroll
        for (int j = 0; j < 4; ++j) acc[i][j] = (f32x4){0.f, 0.f, 0.f, 0.f};

    const float*          hrow = h     + (size_t)(m0 + am) * NH + ak;
    const unsigned short* arow = aware + (size_t)(m0 + am) * NH + ak;
    const float*          wcol = Wcat  + (size_t)bk * NH + n0 + bn;

    float hv[16];
    unsigned int aw[8];
    float wv[16];

    auto stage = [&](int kt) {
        const int region = kt >> 10;
        const int kb = kt & 1023;
        if (region != 1) {
            const float4* hp = (const float4*)(hrow + kb);
            float4 a = hp[0], b = hp[1], c = hp[2], d = hp[3];
            hv[0]=a.x; hv[1]=a.y; hv[2]=a.z; hv[3]=a.w;
            hv[4]=b.x; hv[5]=b.y; hv[6]=b.z; hv[7]=b.w;
            hv[8]=c.x; hv[9]=c.y; hv[10]=c.z; hv[11]=c.w;
            hv[12]=d.x; hv[13]=d.y; hv[14]=d.z; hv[15]=d.w;
        }
        if (region >= 1) {
            const uint4* ap = (const uint4*)(arow + kb);
            uint4 a0 = ap[0], a1 = ap[1];
            aw[0]=a0.x; aw[1]=a0.y; aw[2]=a0.z; aw[3]=a0.w;
            aw[4]=a1.x; aw[5]=a1.y; aw[6]=a1.z; aw[7]=a1.w;
        }
        {
            const float* wp = wcol + (size_t)kt * NH;
#pragma unroll
            for (int j = 0; j < 16; ++j) wv[j] = wp[(size_t)j * NH];
        }
    };

    auto writeStage = [&](int kt) {
        const int region = kt >> 10;
        unsigned int p[8];
        if (region == 0) {
#pragma unroll
            for (int i = 0; i < 8; ++i) p[i] = pk2(hv[2*i], hv[2*i+1]);
        } else if (region == 1) {
#pragma unroll
            for (int i = 0; i < 8; ++i) p[i] = aw[i];
        } else {
#pragma unroll
            for (int i = 0; i < 8; ++i) {
                float lo = hv[2*i]   * bf2f(aw[i] & 0xffffu);
                float hi = hv[2*i+1] * bf2f(aw[i] >> 16);
                p[i] = pk2(lo, hi);
            }
        }
        *(int4*)(Asl + SW64(am*64 + ak*2))      = make_int4(p[0], p[1], p[2], p[3]);
        *(int4*)(Asl + SW64(am*64 + ak*2 + 16)) = make_int4(p[4], p[5], p[6], p[7]);
        unsigned int q[8];
#pragma unroll
        for (int i = 0; i < 8; ++i) q[i] = pk2(wv[2*i], wv[2*i+1]);
        *(int4*)(Bsl + SW64(bn*64 + bk*2))      = make_int4(q[0], q[1], q[2], q[3]);
        *(int4*)(Bsl + SW64(bn*64 + bk*2 + 16)) = make_int4(q[4], q[5], q[6], q[7]);
    };

    stage(0);
    for (int kt = 0; kt < 3072; kt += 32) {
        __syncthreads();
        writeStage(kt);
        __syncthreads();
        if (kt + 32 < 3072) stage(kt + 32);

        bf16x8 af[4], bfr[4];
#pragma unroll
        for (int mf = 0; mf < 4; ++mf)
            af[mf] = *(const bf16x8*)(Asl + SW64((wm + mf*16 + lr)*64 + lk*16));
#pragma unroll
        for (int nf = 0; nf < 4; ++nf)
            bfr[nf] = *(const bf16x8*)(Bsl + SW64((wn + nf*16 + lr)*64 + lk*16));
#pragma unroll
        for (int mf = 0; mf < 4; ++mf)
#pragma unroll
            for (int nf = 0; nf < 4; ++nf)
                acc[mf][nf] = __builtin_amdgcn_mfma_f32_16x16x32_bf16(af[mf], bfr[nf], acc[mf][nf], 0, 0, 0);
    }

#pragma unroll
    for (int nf = 0; nf < 4; ++nf) {
        const int col = n0 + wn + nf*16 + lr;
        const float bc = bcat[col];
#pragma unroll
        for (int mf = 0; mf < 4; ++mf)
#pragma unroll
            for (int r = 0; r < 4; ++r) {
                size_t row = (size_t)(m0 + wm + mf*16 + lk*4 + r);
                float x = acc[mf][nf][r] + bc;
                float g = 0.5f * x * (1.0f + erff(x * 0.70710678118654752f));
                x2[row * NH + col] = f2bf(g);
            }
    }
}

// ---------------------------------------------------------------------------
// Kernel C (fallback): ner_scores = [x2 @ W_crf + b_crf, -10000, -10000]
// ---------------------------------------------------------------------------
__global__ __launch_bounds__(256) void kC(const unsigned short* __restrict__ x2,
                                          const float* __restrict__ Wcrf,
                                          const float* __restrict__ bcrf,
                                          float* __restrict__ out) {
    __shared__ __align__(16) char Asl[8192];
    __shared__ __align__(16) char Bsl[3072];

    const int tid  = threadIdx.x;
    const int lane = tid & 63;
    const int wid  = tid >> 6;
    const int lr   = lane & 15;
    const int lk   = lane >> 4;
    const int m0   = blockIdx.x * 128;
    const int am   = tid >> 1;
    const int ak   = (tid & 1) * 16;

    for (int i = tid; i < 192; i += 256) *(int4*)(Bsl + i*16) = make_int4(0, 0, 0, 0);

    f32x4 acc[2][3];
#pragma unroll
    for (int i = 0; i < 2; ++i)
#pragma unroll
        for (int j = 0; j < 3; ++j) acc[i][j] = (f32x4){0.f, 0.f, 0.f, 0.f};

    const unsigned short* xrow = x2 + (size_t)(m0 + am) * NH + ak;

    for (int kt = 0; kt < NH; kt += 32) {
        const uint4* xp = (const uint4*)(xrow + kt);
        uint4 x0 = xp[0], x1 = xp[1];
        float wv[5];
#pragma unroll
        for (int p = 0; p < 5; ++p) {
            int i = tid + p * 256;
            wv[p] = (i < 32*NT) ? Wcrf[(size_t)kt * NT + i] : 0.f;
        }
        __syncthreads();
        *(uint4*)(Asl + SW64(am*64 + ak*2))      = x0;
        *(uint4*)(Asl + SW64(am*64 + ak*2 + 16)) = x1;
#pragma unroll
        for (int p = 0; p < 5; ++p) {
            int i = tid + p * 256;
            if (i < 32*NT) {
                int kk = i / NT;
                int t  = i - kk * NT;
                *(unsigned short*)(Bsl + SW64(t*64 + kk*2)) = f2bf(wv[p]);
            }
        }
        __syncthreads();
        bf16x8 af[2], bfr[3];
#pragma unroll
        for (int mf = 0; mf < 2; ++mf)
            af[mf] = *(const bf16x8*)(Asl + SW64((wid*32 + mf*16 + lr)*64 + lk*16));
#pragma unroll
        for (int nf = 0; nf < 3; ++nf)
            bfr[nf] = *(const bf16x8*)(Bsl + SW64((nf*16 + lr)*64 + lk*16));
#pragma unroll
        for (int mf = 0; mf < 2; ++mf)
#pragma unroll
            for (int nf = 0; nf < 3; ++nf)
                acc[mf][nf] = __builtin_amdgcn_mfma_f32_16x16x32_bf16(af[mf], bfr[nf], acc[mf][nf], 0, 0, 0);
    }

#pragma unroll
    for (int nf = 0; nf < 3; ++nf) {
        const int t = nf*16 + lr;
        const float bc = (t < NT) ? bcrf[t] : 0.f;
#pragma unroll
        for (int mf = 0; mf < 2; ++mf)
#pragma unroll
            for (int r = 0; r < 4; ++r) {
                size_t row = (size_t)(m0 + wid*32 + mf*16 + lk*4 + r);
                if (t < NT)       out[row * NLP + t] = acc[mf][nf][r] + bc;
                else if (t < NLP) out[row * NLP + t] = -10000.0f;
            }
    }
}

// ---------------------------------------------------------------------------
// Kernel Dold (fallback): round-11 exp-domain scan, scores staged in LDS.
// ---------------------------------------------------------------------------
#define CRFSTEP(EL) do {                                   \
    float as_[37];                                         \
    _Pragma("unroll")                                      \
    for (int f_ = 0; f_ < 37; ++f_) as_[f_] = rl(a, f_);   \
    __builtin_amdgcn_sched_barrier(0);                     \
    float c0 = 0.f, c1 = 0.f, c2 = 0.f, c3 = 0.f;          \
    _Pragma("unroll")                                      \
    for (int f_ = 0; f_ < 36; f_ += 4) {                   \
        c0 = fmaf(as_[f_    ], trow[f_    ], c0);          \
        c1 = fmaf(as_[f_ + 1], trow[f_ + 1], c1);          \
        c2 = fmaf(as_[f_ + 2], trow[f_ + 2], c2);          \
        c3 = fmaf(as_[f_ + 3], trow[f_ + 3], c3);          \
    }                                                      \
    c0 = fmaf(as_[36], trow[36], c0);                      \
    a = (EL) * ((c0 + c1) + (c2 + c3));                    \
} while (0)

__global__ __launch_bounds__(256) void kDold(const float* __restrict__ scores,
                                             const int* __restrict__ labels,
                                             const int* __restrict__ lens,
                                             const float* __restrict__ trans,
                                             float* __restrict__ loss) {
    __shared__ float S[NS * NLP];
    __shared__ float trL[39 * 41];
    __shared__ int   labL[NS];
    __shared__ float gred[4];

    const int b    = blockIdx.x;
    const int tid  = threadIdx.x;
    const int lane = tid & 63;
    const int wid  = tid >> 6;
    const int len  = lens[b];
    const float* sb = scores + (size_t)b * NS * NLP;

    {
        const int n4 = (len * NLP + 3) >> 2;
        const float4* src = (const float4*)sb;
        float4* dst = (float4*)S;
        for (int i = tid; i < n4; i += 256) dst[i] = src[i];
    }
    for (int i = tid; i < NS; i += 256) labL[i] = labels[b * NS + i];
    for (int idx = tid; idx < 39 * 39; idx += 256) {
        int to = idx / 39, f = idx - to * 39;
        trL[to * 41 + f] = trans[idx];
    }
    __syncthreads();

    float g = 0.0f;
    for (int t = tid; t < len; t += 256) g += S[t * NLP + labL[t]];
    for (int i = tid; i <= len; i += 256) {
        int frm = (i == 0) ? 37 : labL[i - 1];
        int to  = (i == len) ? 38 : labL[i];
        g += trL[to * 41 + frm];
    }
#pragma unroll
    for (int off = 32; off > 0; off >>= 1) g += __shfl_xor(g, off, 64);
    if (lane == 0) gred[wid] = g;
    __syncthreads();

    if (wid != 0) return;

    const float gold = (gred[0] + gred[1]) + (gred[2] + gred[3]);

    const int myrow = (lane < 39) ? lane : 0;
    float trow[39];
#pragma unroll
    for (int f = 0; f < 39; ++f) trow[f] = __expf(trL[myrow * 41 + f]);
    const float trEnd = (lane < 39) ? trL[38 * 41 + lane] : 0.f;
    const bool act = (lane < 39);

    float l0 = act ? S[lane] : -10000.f;
    float a = act ? __expf(l0) * trow[37] : 0.f;
    float C = 0.0f;

    auto ldrow = [&](int r) {
        r = (r < len) ? r : (len - 1);
        return S[act ? (r * NLP + lane) : 0];
    };
    float lg0 = ldrow(1), lg1 = ldrow(2), lg2 = ldrow(3), lg3 = ldrow(4);

    int t = 1;
    for (; t + 3 < len; t += 4) {
        float e0 = __expf(lg0), e1 = __expf(lg1), e2 = __expf(lg2), e3 = __expf(lg3);
        lg0 = ldrow(t + 4); lg1 = ldrow(t + 5); lg2 = ldrow(t + 6); lg3 = ldrow(t + 7);
        CRFSTEP(e0); CRFSTEP(e1); CRFSTEP(e2); CRFSTEP(e3);
        float s = rl(a, 0);
        float rr = __builtin_amdgcn_rcpf(s);
        a *= rr; C -= __logf(rr);
    }
    for (; t < len; ++t) {
        float el = __expf(ldrow(t));
        CRFSTEP(el);
    }

    float aend = (act && a > 0.f) ? C + __logf(a) + trEnd : -1e30f;
    float mx = aend;
#pragma unroll
    for (int off = 32; off > 0; off >>= 1) mx = fmaxf(mx, __shfl_xor(mx, off, 64));
    float es = act ? __expf(aend - mx) : 0.0f;
#pragma unroll
    for (int off = 32; off > 0; off >>= 1) es += __shfl_xor(es, off, 64);
    float norm = mx + __logf(es);

    if (lane == 0) loss[b] = gold - norm;
}

// ---------------------------------------------------------------------------
extern "C" void kernel_launch(void* const* d_in, const int* in_sizes, int n_in,
                              void* d_out, int out_size, void* d_ws, size_t ws_size,
                              hipStream_t stream) {
    const float* h        = (const float*)d_in[0];
    const int* token_nums = (const int*)d_in[2];
    const int* labels     = (const int*)d_in[3];
    const float* bio      = (const float*)d_in[4];
    const float* Wcat     = (const float*)d_in[5];
    const float* bcat     = (const float*)d_in[6];
    const float* Wcrf     = (const float*)d_in[7];
    const float* bcrf     = (const float*)d_in[8];
    const float* trans    = (const float*)d_in[9];

    float* out = (float*)d_out;
    unsigned short* attn  = (unsigned short*)d_out;  // 2MB scratch, overwritten by kCr

    const size_t ASW_BYTES = (size_t)128 * 48 * 16384;        // 96 MB
    const size_t P_BYTES   = (size_t)4 * NM * 48 * 4;         // 12.6 MB
    const size_t WSW_BYTES = (size_t)8 * 48 * 16384;          // 6 MB
    const size_t WT_BYTES  = (size_t)48 * 3072 * 2;           // 288 KB
    const size_t PM_BYTES  = (size_t)NB * 8 * 2304 * 4;       // 2.36 MB
    const size_t PC_BYTES  = (size_t)NB * 8 * 4;              // 1 KB
    const bool fast = ws_size >= ASW_BYTES + P_BYTES + WSW_BYTES + WT_BYTES + PM_BYTES + PC_BYTES;

    hipLaunchKernelGGL(kA1, dim3(NM / 128), dim3(512), 0, stream, h, bio, attn);

    if (fast) {
        char*  Asw = (char*)d_ws;
        float* P   = (float*)((char*)d_ws + ASW_BYTES);
        char*  Wsw = (char*)d_ws + ASW_BYTES + P_BYTES;
        unsigned short* WT = (unsigned short*)((char*)d_ws + ASW_BYTES + P_BYTES + WSW_BYTES);
        float* Pm  = (float*)((char*)d_ws + ASW_BYTES + P_BYTES + WSW_BYTES + WT_BYTES);
        float* Pc  = Pm + (size_t)NB * 8 * 2304;

        hipLaunchKernelGGL(kW, dim3(8 * 48), dim3(256), 0, stream, Wcat, Wsw);
        hipLaunchKernelGGL(kW2, dim3(72), dim3(256), 0, stream, Wcrf, WT);
        hipLaunchKernelGGL(kA2f, dim3(NH / 128, NM / 128), dim3(256), 0, stream,
                           attn, bio, h, Asw);
        hipLaunchKernelGGL(kBf, dim3(256), dim3(512), 0, stream, Asw, Wsw, bcat, WT, P);
        hipLaunchKernelGGL(kCr, dim3(256), dim3(256), 0, stream, P, bcrf, out);
        hipLaunchKernelGGL(kDm, dim3(NB * 8), dim3(64), 0, stream, out, token_nums, trans,
                           Pm, Pc);
        hipLaunchKernelGGL(kDc, dim3(NB), dim3(256), 0, stream, out, labels, token_nums,
                           trans, Pm, Pc, out + (size_t)NM * NLP);
    } else {
        unsigned short* aware = (unsigned short*)d_ws;
        unsigned short* x2    = aware + (size_t)NM * NH;

        hipLaunchKernelGGL(kA2, dim3(NH / 128, NM / 128), dim3(256), 0, stream, attn, bio, aware);
        hipLaunchKernelGGL(kB, dim3((NH / 128) * (NM / 128)), dim3(256), 0, stream,
                           h, aware, Wcat, bcat, x2);
        hipLaunchKernelGGL(kC, dim3(NM / 128), dim3(256), 0, stream, x2, Wcrf, bcrf, out);
        hipLaunchKernelGGL(kDold, dim3(NB), dim3(256), 0, stream, out, labels, token_nums,
                           trans, out + (size_t)NM * NLP);
    }
}

// Round 14
// 226.433 us; speedup vs baseline: 1.4573x; 1.0809x over previous
//
#include <hip/hip_runtime.h>
#include <hip/hip_bf16.h>
#include <math.h>

#define NB 32
#define NS 512
#define NH 1024
#define NT 37
#define NLP 39
#define NM (NB*NS)   // 16384

typedef __attribute__((ext_vector_type(8))) short bf16x8;
typedef __attribute__((ext_vector_type(4))) float f32x4;

__device__ __forceinline__ float bf2f(unsigned int u) {
    unsigned int x = u << 16;
    float f;
    __builtin_memcpy(&f, &x, 4);
    return f;
}
__device__ __forceinline__ unsigned short f2bf(float f) {
    __hip_bfloat16 hb = __float2bfloat16(f);
    unsigned short u;
    __builtin_memcpy(&u, &hb, 2);
    return u;
}
__device__ __forceinline__ unsigned int pk2(float lo, float hi) {
    return ((unsigned int)f2bf(hi) << 16) | (unsigned int)f2bf(lo);
}
// bijective XOR swizzle for [row][64B] bf16 LDS tiles
__device__ __forceinline__ int SW64(int b)  { return b ^ ((b >> 2) & 0x70); }
// tile swizzle for [128/256 row][64 k] bf16 tiles (row stride 128B)
__device__ __forceinline__ int TSW(int row, int kcolByte) {
    return (row * 128 + kcolByte) ^ ((row & 7) << 4);
}
__device__ __forceinline__ float rl(float x, int l) {
    return __int_as_float(__builtin_amdgcn_readlane(__float_as_int(x), l));
}
__device__ __forceinline__ void gld16(const void* g, void* l) {
    __builtin_amdgcn_global_load_lds((const __attribute__((address_space(1))) void*)g,
                                     (__attribute__((address_space(3))) void*)l, 16, 0, 0);
}
#define VMW(N) asm volatile("s_waitcnt vmcnt(" #N ")" ::: "memory")
#define BARR() do { __builtin_amdgcn_s_barrier(); __builtin_amdgcn_sched_barrier(0); } while (0)

// ---------------------------------------------------------------------------
// Kernel Pre (fast): fused kA1 + kW + kW2, 548 blocks x 512 thr.
//  bid <128  : kA1 work (scores->softmax->attn) AND writes Asw region 0
//              (h as bf16, tile-major TSW) from the fragments it already holds.
//  bid <512  : kW (Wcat -> Wsw swizzled tiles), tile = bid-128.
//  else      : kW2 (Wcrf^T prepack), idx = (bid-512)*512+tid.
// ---------------------------------------------------------------------------
__global__ __launch_bounds__(512) void kPre(const float* __restrict__ h,
                                            const float* __restrict__ bio,
                                            const float* __restrict__ Wcat,
                                            const float* __restrict__ Wcrf,
                                            unsigned short* __restrict__ attn,
                                            char* __restrict__ Asw,
                                            char* __restrict__ Wsw,
                                            unsigned short* __restrict__ WT) {
    __shared__ __align__(16) char shmem[48 * 2048];   // 96KB, aliased per branch
    const int bid = blockIdx.x;
    const int tid = threadIdx.x;

    if (bid < 128) {
        // ---------------- kA1 + region-0 writes ----------------
        char* Bl = shmem;
        const int lane = tid & 63;
        const int wid  = tid >> 6;
        const int lr   = lane & 15;
        const int lk   = lane >> 4;
        const int m0   = bid * 128;

        for (int idx = tid; idx < 37 * 256; idx += 512) {
            int t = idx >> 8, k4 = idx & 255;
            float4 v = *(const float4*)&bio[(size_t)t * NH + k4 * 4];
            int byte = (t * 2048 + k4 * 8) ^ ((t & 7) << 4);
            *(uint2*)(Bl + byte) = make_uint2(pk2(v.x, v.y), pk2(v.z, v.w));
        }
        for (int idx = tid; idx < 11 * 256; idx += 512) {
            int t = 37 + (idx >> 8), k4 = idx & 255;
            int byte = (t * 2048 + k4 * 8) ^ ((t & 7) << 4);
            *(uint2*)(Bl + byte) = make_uint2(0, 0);
        }
        __syncthreads();

        const int arow = m0 + wid * 16 + lr;
        const float* hp = h + (size_t)arow * NH + lk * 8;
        const int trow = wid * 16 + lr;          // within-tile row

        f32x4 sacc[3];
#pragma unroll
        for (int j = 0; j < 3; ++j) sacc[j] = (f32x4){0.f, 0.f, 0.f, 0.f};

        float4 p0 = *(const float4*)(hp);
        float4 p1 = *(const float4*)(hp + 4);
        for (int kt = 0; kt < NH; kt += 32) {
            float4 c0 = p0, c1 = p1;
            if (kt + 32 < NH) {
                p0 = *(const float4*)(hp + kt + 32);
                p1 = *(const float4*)(hp + kt + 36);
            }
            union { unsigned int u[4]; bf16x8 v; uint4 q; } af;
            af.u[0] = pk2(c0.x, c0.y); af.u[1] = pk2(c0.z, c0.w);
            af.u[2] = pk2(c1.x, c1.y); af.u[3] = pk2(c1.z, c1.w);
            // region-0 write: h as bf16, tile-major swizzled
            {
                int kg = kt + lk * 8;
                size_t tb = ((size_t)bid * 48 + (kg >> 6)) * 16384;
                *(uint4*)(Asw + tb + TSW(trow, (kg & 63) * 2)) = af.q;
            }
#pragma unroll
            for (int nf = 0; nf < 3; ++nf) {
                int t = nf * 16 + lr;
                int byte = (t * 2048 + (kt + lk * 8) * 2) ^ ((t & 7) << 4);
                bf16x8 bf = *(const bf16x8*)(Bl + byte);
                sacc[nf] = __builtin_amdgcn_mfma_f32_16x16x32_bf16(af.v, bf, sacc[nf], 0, 0, 0);
            }
        }

#pragma unroll
        for (int r = 0; r < 4; ++r) {
            const int orow = wid * 16 + lk * 4 + r;
            float s0 = sacc[0][r] * 0.03125f;
            float s1 = sacc[1][r] * 0.03125f;
            float s2 = sacc[2][r] * 0.03125f;
            const bool v2 = (lr < 5);
            float mx = fmaxf(fmaxf(s0, s1), v2 ? s2 : -1e30f);
#pragma unroll
            for (int d = 1; d < 16; d <<= 1) mx = fmaxf(mx, __shfl_xor(mx, d, 64));
            float e0 = __expf(s0 - mx), e1 = __expf(s1 - mx);
            float e2 = v2 ? __expf(s2 - mx) : 0.f;
            float sm = e0 + e1 + e2;
#pragma unroll
            for (int d = 1; d < 16; d <<= 1) sm += __shfl_xor(sm, d, 64);
            float inv = 1.f / sm;
            size_t g = (size_t)(m0 + orow) * 64;
            attn[g + lr]      = f2bf(e0 * inv);
            attn[g + 16 + lr] = f2bf(e1 * inv);
            attn[g + 32 + lr] = f2bf(e2 * inv);
            attn[g + 48 + lr] = 0;
        }
    } else if (bid < 512) {
        // ---------------- kW: Wcat -> Wsw swizzled tiles ----------------
        unsigned short* wt = (unsigned short*)shmem;   // 16KB
        const int tile = bid - 128;
        const int tn   = tile / 48;
        const int tk   = tile - tn * 48;
        const int n00  = tn * 128;
        const int k0   = tk * 64;

        for (int lin = tid; lin < 2048; lin += 512) {
            int kk = lin >> 5, ng = lin & 31;
            float4 v = *(const float4*)&Wcat[(size_t)(k0 + kk) * NH + n00 + ng * 4];
            *(uint2*)&wt[kk * 128 + ng * 4] = make_uint2(pk2(v.x, v.y), pk2(v.z, v.w));
        }
        __syncthreads();
        for (int lin = tid; lin < 1024; lin += 512) {
            int rn = lin >> 3, kg = lin & 7;
            unsigned short t8[8];
#pragma unroll
            for (int j = 0; j < 8; ++j) t8[j] = wt[(kg * 8 + j) * 128 + rn];
            uint4 v;
            __builtin_memcpy(&v, t8, 16);
            *(uint4*)(Wsw + (size_t)tile * 16384 + TSW(rn, kg * 16)) = v;
        }
    } else {
        // ---------------- kW2: Wcrf^T prepack ----------------
        const int idx = (bid - 512) * 512 + tid;
        if (idx < 48 * 384) {
            const int t = idx / 384, kg = idx - t * 384;
            unsigned short v[8];
#pragma unroll
            for (int e = 0; e < 8; ++e) {
                int k = kg * 8 + e;
                v[e] = (t < NT) ? f2bf(Wcrf[(size_t)k * NT + t]) : (unsigned short)0;
            }
            uint4 w;
            __builtin_memcpy(&w, v, 16);
            *(uint4*)(WT + (size_t)t * 3072 + kg * 8) = w;
        }
    }
}

// ---------------------------------------------------------------------------
// Kernel A1 (fallback): scores -> softmax -> attn only.
// ---------------------------------------------------------------------------
__global__ __launch_bounds__(512) void kA1(const float* __restrict__ h,
                                           const float* __restrict__ bio,
                                           unsigned short* __restrict__ attn) {
    __shared__ __align__(16) char Bl[48 * 2048];

    const int tid  = threadIdx.x;
    const int lane = tid & 63;
    const int wid  = tid >> 6;
    const int lr   = lane & 15;
    const int lk   = lane >> 4;
    const int m0   = blockIdx.x * 128;

    for (int idx = tid; idx < 37 * 256; idx += 512) {
        int t = idx >> 8, k4 = idx & 255;
        float4 v = *(const float4*)&bio[(size_t)t * NH + k4 * 4];
        int byte = (t * 2048 + k4 * 8) ^ ((t & 7) << 4);
        *(uint2*)(Bl + byte) = make_uint2(pk2(v.x, v.y), pk2(v.z, v.w));
    }
    for (int idx = tid; idx < 11 * 256; idx += 512) {
        int t = 37 + (idx >> 8), k4 = idx & 255;
        int byte = (t * 2048 + k4 * 8) ^ ((t & 7) << 4);
        *(uint2*)(Bl + byte) = make_uint2(0, 0);
    }
    __syncthreads();

    const int arow = m0 + wid * 16 + lr;
    const float* hp = h + (size_t)arow * NH + lk * 8;

    f32x4 sacc[3];
#pragma unroll
    for (int j = 0; j < 3; ++j) sacc[j] = (f32x4){0.f, 0.f, 0.f, 0.f};

    float4 p0 = *(const float4*)(hp);
    float4 p1 = *(const float4*)(hp + 4);
    for (int kt = 0; kt < NH; kt += 32) {
        float4 c0 = p0, c1 = p1;
        if (kt + 32 < NH) {
            p0 = *(const float4*)(hp + kt + 32);
            p1 = *(const float4*)(hp + kt + 36);
        }
        union { unsigned int u[4]; bf16x8 v; } af;
        af.u[0] = pk2(c0.x, c0.y); af.u[1] = pk2(c0.z, c0.w);
        af.u[2] = pk2(c1.x, c1.y); af.u[3] = pk2(c1.z, c1.w);
#pragma unroll
        for (int nf = 0; nf < 3; ++nf) {
            int t = nf * 16 + lr;
            int byte = (t * 2048 + (kt + lk * 8) * 2) ^ ((t & 7) << 4);
            bf16x8 bf = *(const bf16x8*)(Bl + byte);
            sacc[nf] = __builtin_amdgcn_mfma_f32_16x16x32_bf16(af.v, bf, sacc[nf], 0, 0, 0);
        }
    }

#pragma unroll
    for (int r = 0; r < 4; ++r) {
        const int orow = wid * 16 + lk * 4 + r;
        float s0 = sacc[0][r] * 0.03125f;
        float s1 = sacc[1][r] * 0.03125f;
        float s2 = sacc[2][r] * 0.03125f;
        const bool v2 = (lr < 5);
        float mx = fmaxf(fmaxf(s0, s1), v2 ? s2 : -1e30f);
#pragma unroll
        for (int d = 1; d < 16; d <<= 1) mx = fmaxf(mx, __shfl_xor(mx, d, 64));
        float e0 = __expf(s0 - mx), e1 = __expf(s1 - mx);
        float e2 = v2 ? __expf(s2 - mx) : 0.f;
        float sm = e0 + e1 + e2;
#pragma unroll
        for (int d = 1; d < 16; d <<= 1) sm += __shfl_xor(sm, d, 64);
        float inv = 1.f / sm;
        size_t g = (size_t)(m0 + orow) * 64;
        attn[g + lr]      = f2bf(e0 * inv);
        attn[g + 16 + lr] = f2bf(e1 * inv);
        attn[g + 32 + lr] = f2bf(e2 * inv);
        attn[g + 48 + lr] = 0;
    }
}

// ---------------------------------------------------------------------------
// Kernel A2 (fallback): aware = attn @ bio, plain bf16 row-major out.
// ---------------------------------------------------------------------------
__global__ __launch_bounds__(256) void kA2(const unsigned short* __restrict__ attn,
                                           const float* __restrict__ bio,
                                           unsigned short* __restrict__ aware) {
    __shared__ __align__(16) char Bsl[128 * 64];

    const int tid  = threadIdx.x;
    const int lane = tid & 63;
    const int wid  = tid >> 6;
    const int wm   = (wid >> 1) * 64;
    const int wn   = (wid & 1) * 64;
    const int lr   = lane & 15;
    const int lk   = lane >> 4;
    const int n0   = blockIdx.x * 128;
    const int m0   = blockIdx.y * 128;

    const int bn = tid & 127;
    const int bq = (tid >> 7) * 16;

    f32x4 acc[4][4];
#pragma unroll
    for (int i = 0; i < 4; ++i)
#pragma unroll
        for (int j = 0; j < 4; ++j) acc[i][j] = (f32x4){0.f, 0.f, 0.f, 0.f};

#pragma unroll
    for (int ks = 0; ks < 2; ++ks) {
        unsigned int p[8];
#pragma unroll
        for (int i = 0; i < 8; ++i) {
            int t0 = ks*32 + bq + 2*i;
            float lo = (t0     < NT) ? bio[(size_t)t0 * NH + n0 + bn]       : 0.f;
            float hi = (t0 + 1 < NT) ? bio[(size_t)(t0+1) * NH + n0 + bn]   : 0.f;
            p[i] = pk2(lo, hi);
        }
        __syncthreads();
        *(int4*)(Bsl + SW64(bn*64 + bq*2))      = make_int4(p[0], p[1], p[2], p[3]);
        *(int4*)(Bsl + SW64(bn*64 + bq*2 + 16)) = make_int4(p[4], p[5], p[6], p[7]);
        __syncthreads();

        bf16x8 af[4];
#pragma unroll
        for (int mf = 0; mf < 4; ++mf)
            af[mf] = *(const bf16x8*)(attn + (size_t)(m0 + wm + mf*16 + lr) * 64 + ks*32 + lk*8);
#pragma unroll
        for (int nf = 0; nf < 4; ++nf) {
            bf16x8 bb = *(const bf16x8*)(Bsl + SW64((wn + nf*16 + lr)*64 + lk*16));
#pragma unroll
            for (int mf = 0; mf < 4; ++mf)
                acc[mf][nf] = __builtin_amdgcn_mfma_f32_16x16x32_bf16(af[mf], bb, acc[mf][nf], 0, 0, 0);
        }
    }

#pragma unroll
    for (int mf = 0; mf < 4; ++mf)
#pragma unroll
        for (int nf = 0; nf < 4; ++nf)
#pragma unroll
            for (int r = 0; r < 4; ++r) {
                size_t row = (size_t)(m0 + wm + mf*16 + lk*4 + r);
                aware[row * NH + n0 + wn + nf*16 + lr] = f2bf(acc[mf][nf][r]);
            }
}

// ---------------------------------------------------------------------------
// Kernel A2f (fast, v2): computes aware chunk; reads h as bf16 from Asw
// region 0 (written by kPre); writes only regions 1 (aware) and 2 (h*aware).
// ---------------------------------------------------------------------------
__global__ __launch_bounds__(256) void kA2f(const unsigned short* __restrict__ attn,
                                            const float* __restrict__ bio,
                                            char* __restrict__ Asw) {
    __shared__ __align__(16) char Bsl[128 * 64];
    __shared__ __align__(16) unsigned short awL[128 * 128];  // 32KB aware chunk

    const int tid  = threadIdx.x;
    const int lane = tid & 63;
    const int wid  = tid >> 6;
    const int wm   = (wid >> 1) * 64;
    const int wn   = (wid & 1) * 64;
    const int lr   = lane & 15;
    const int lk   = lane >> 4;
    const int n0   = blockIdx.x * 128;
    const int m0   = blockIdx.y * 128;
    const int tm   = blockIdx.y;

    const int bn = tid & 127;
    const int bq = (tid >> 7) * 16;

    f32x4 acc[4][4];
#pragma unroll
    for (int i = 0; i < 4; ++i)
#pragma unroll
        for (int j = 0; j < 4; ++j) acc[i][j] = (f32x4){0.f, 0.f, 0.f, 0.f};

#pragma unroll
    for (int ks = 0; ks < 2; ++ks) {
        unsigned int p[8];
#pragma unroll
        for (int i = 0; i < 8; ++i) {
            int t0 = ks*32 + bq + 2*i;
            float lo = (t0     < NT) ? bio[(size_t)t0 * NH + n0 + bn]       : 0.f;
            float hi = (t0 + 1 < NT) ? bio[(size_t)(t0+1) * NH + n0 + bn]   : 0.f;
            p[i] = pk2(lo, hi);
        }
        __syncthreads();
        *(int4*)(Bsl + SW64(bn*64 + bq*2))      = make_int4(p[0], p[1], p[2], p[3]);
        *(int4*)(Bsl + SW64(bn*64 + bq*2 + 16)) = make_int4(p[4], p[5], p[6], p[7]);
        __syncthreads();

        bf16x8 af[4];
#pragma unroll
        for (int mf = 0; mf < 4; ++mf)
            af[mf] = *(const bf16x8*)(attn + (size_t)(m0 + wm + mf*16 + lr) * 64 + ks*32 + lk*8);
#pragma unroll
        for (int nf = 0; nf < 4; ++nf) {
            bf16x8 bb = *(const bf16x8*)(Bsl + SW64((wn + nf*16 + lr)*64 + lk*16));
#pragma unroll
            for (int mf = 0; mf < 4; ++mf)
                acc[mf][nf] = __builtin_amdgcn_mfma_f32_16x16x32_bf16(af[mf], bb, acc[mf][nf], 0, 0, 0);
        }
    }

#pragma unroll
    for (int mf = 0; mf < 4; ++mf)
#pragma unroll
        for (int nf = 0; nf < 4; ++nf)
#pragma unroll
            for (int r = 0; r < 4; ++r)
                awL[(wm + mf*16 + lk*4 + r) * 128 + wn + nf*16 + lr] = f2bf(acc[mf][nf][r]);
    __syncthreads();

    // region 1 (aware)
#pragma unroll
    for (int i = 0; i < 8; ++i) {
        int lin = tid + i * 256;
        int row = lin >> 4, kg = lin & 15;
        uint4 v = *(const uint4*)&awL[row * 128 + kg * 8];
        int kglob = 1024 + n0 + kg * 8;
        size_t tbase = ((size_t)tm * 48 + (kglob >> 6)) * 16384;
        *(uint4*)(Asw + tbase + TSW(row, (kglob & 63) * 2)) = v;
    }
    // region 2 (h*aware), h read back as bf16 from region 0
#pragma unroll
    for (int i = 0; i < 8; ++i) {
        int lin = tid + i * 256;
        int row = lin >> 4, kg = lin & 15;
        int k0g = n0 + kg * 8;
        size_t tb0 = ((size_t)tm * 48 + (k0g >> 6)) * 16384;
        uint4 hv4 = *(const uint4*)(Asw + tb0 + TSW(row, (k0g & 63) * 2));
        unsigned int hu[4] = {hv4.x, hv4.y, hv4.z, hv4.w};
        uint4 awv = *(const uint4*)&awL[row * 128 + kg * 8];
        unsigned int awu[4] = {awv.x, awv.y, awv.z, awv.w};
        unsigned int p2[4];
#pragma unroll
        for (int j = 0; j < 4; ++j) {
            float lo = bf2f(hu[j] & 0xffffu) * bf2f(awu[j] & 0xffffu);
            float hi = bf2f(hu[j] >> 16)     * bf2f(awu[j] >> 16);
            p2[j] = pk2(lo, hi);
        }
        int k2g = 2048 + n0 + kg * 8;
        size_t tb2 = ((size_t)tm * 48 + (k2g >> 6)) * 16384;
        *(uint4*)(Asw + tb2 + TSW(row, (k2g & 63) * 2)) = make_uint4(p2[0], p2[1], p2[2], p2[3]);
    }
}

// ---------------------------------------------------------------------------
// Kernel W (fallback-support for fast gate fail is not needed; kept for safety
// in case of future use) -- NOTE: fast path uses kPre instead.
// ---------------------------------------------------------------------------
// (removed; kPre handles it)

// ---------------------------------------------------------------------------
// Kernel Bf (fast): 256x256 tile bf16 GEMM, BK=64, 8 waves, counted-vmcnt
// 4-phase schedule + fused kC epilogue (prepacked Wcrf^T). (round-11 proven)
// ---------------------------------------------------------------------------
__global__ __launch_bounds__(512, 2) void kBf(const char* __restrict__ Asw,
                                              const char* __restrict__ Wsw,
                                              const float* __restrict__ bcat,
                                              const unsigned short* __restrict__ WT,
                                              float* __restrict__ P) {
    __shared__ __align__(16) char lds[131072];  // A: buf*32768+h*16384; B at +65536

    const int tid  = threadIdx.x;
    const int lane = tid & 63;
    const int wid  = tid >> 6;
    const int widm = wid >> 2;       // 0..1
    const int widn = wid & 3;        // 0..3
    const int lr   = lane & 15;
    const int lk   = lane >> 4;

    const int id   = blockIdx.x;     // 256 blocks
    const int xcd  = id & 7;
    const int slot = id >> 3;        // 0..31
    const int Mt   = xcd * 8 + (slot >> 2);
    const int Nt   = slot & 3;
    const int m0   = Mt * 256, n0 = Nt * 256;
    const int soff = tid * 16;

    f32x4 acc00[4][2], acc01[4][2], acc10[4][2], acc11[4][2];
#pragma unroll
    for (int i = 0; i < 4; ++i)
#pragma unroll
        for (int j = 0; j < 2; ++j) {
            acc00[i][j] = (f32x4){0.f,0.f,0.f,0.f};
            acc01[i][j] = (f32x4){0.f,0.f,0.f,0.f};
            acc10[i][j] = (f32x4){0.f,0.f,0.f,0.f};
            acc11[i][j] = (f32x4){0.f,0.f,0.f,0.f};
        }

    auto stageHalf = [&](int T, int ph) {
        const bool isA = (ph == 0) || (ph == 3);
        const int  h   = isA ? (ph == 3 ? 1 : 0) : (ph - 1);
        const char* src = isA
            ? Asw + ((size_t)((2*Mt + h) * 48 + T)) * 16384
            : Wsw + ((size_t)((2*Nt + h) * 48 + T)) * 16384;
        char* dst = lds + (isA ? 0 : 65536) + (T & 1) * 32768 + h * 16384;
        gld16(src + soff,        dst + soff);
        gld16(src + soff + 8192, dst + soff + 8192);
    };
    auto loadA = [&](bf16x8 (&af)[4][2], int q, int half) {
        const char* base = lds + q * 32768 + half * 16384;
#pragma unroll
        for (int i = 0; i < 4; ++i) {
            int row = widm * 64 + i * 16 + lr;
#pragma unroll
            for (int kk = 0; kk < 2; ++kk)
                af[i][kk] = *(const bf16x8*)(base + TSW(row, kk * 64 + lk * 16));
        }
    };
    auto loadB = [&](bf16x8 (&bfr)[2][2], int q, int half) {
        const char* base = lds + 65536 + q * 32768 + half * 16384;
#pragma unroll
        for (int j = 0; j < 2; ++j) {
            int col = widn * 32 + j * 16 + lr;
#pragma unroll
            for (int kk = 0; kk < 2; ++kk)
                bfr[j][kk] = *(const bf16x8*)(base + TSW(col, kk * 64 + lk * 16));
        }
    };
    auto mma = [&](f32x4 (&ac)[4][2], bf16x8 (&af)[4][2], bf16x8 (&bfr)[2][2]) {
        __builtin_amdgcn_s_setprio(1);
#pragma unroll
        for (int kk = 0; kk < 2; ++kk)
#pragma unroll
            for (int i = 0; i < 4; ++i)
#pragma unroll
                for (int j = 0; j < 2; ++j)
                    ac[i][j] = __builtin_amdgcn_mfma_f32_16x16x32_bf16(
                        af[i][kk], bfr[j][kk], ac[i][j], 0, 0, 0);
        __builtin_amdgcn_s_setprio(0);
    };

    stageHalf(0, 0); stageHalf(0, 1); stageHalf(0, 2); stageHalf(0, 3);
    VMW(0);
    BARR();

    for (int T = 0; T < 47; ++T) {
        const int q = T & 1;
        bf16x8 af0[4][2], af1[4][2], bf0[2][2], bf1[2][2];
        stageHalf(T + 1, 0);
        VMW(6);
        BARR();
        loadA(af0, q, 0); loadB(bf0, q, 0);
        mma(acc00, af0, bf0);
        stageHalf(T + 1, 1);
        VMW(6);
        BARR();
        loadB(bf1, q, 1);
        mma(acc01, af0, bf1);
        stageHalf(T + 1, 2);
        VMW(6);
        BARR();
        loadA(af1, q, 1);
        mma(acc10, af1, bf0);
        stageHalf(T + 1, 3);
        BARR();
        mma(acc11, af1, bf1);
    }
    {   // T = 47 (buf 1), tail waits 4/2/0
        const int q = 1;
        bf16x8 af0[4][2], af1[4][2], bf0[2][2], bf1[2][2];
        VMW(4);
        BARR();
        loadA(af0, q, 0); loadB(bf0, q, 0);
        mma(acc00, af0, bf0);
        VMW(2);
        BARR();
        loadB(bf1, q, 1);
        mma(acc01, af0, bf1);
        VMW(0);
        BARR();
        loadA(af1, q, 1);
        mma(acc10, af1, bf0);
        BARR();
        mma(acc11, af1, bf1);
    }

    // ---------------- fused kC epilogue ----------------
    __syncthreads();
    auto stashQ = [&](f32x4 (&ac)[4][2], int a, int b) {
#pragma unroll
        for (int j = 0; j < 2; ++j) {
            const int lcol = b * 128 + widn * 32 + j * 16 + lr;
            const int kc = lcol >> 6, kk = lcol & 63;
            const float bc = bcat[n0 + lcol];
#pragma unroll
            for (int i = 0; i < 4; ++i)
#pragma unroll
                for (int r = 0; r < 4; ++r) {
                    int lrow = a * 128 + widm * 64 + i * 16 + lk * 4 + r;
                    float x = ac[i][j][r] + bc;
                    float g = 0.5f * x * (1.0f + erff(x * 0.70710678118654752f));
                    *(unsigned short*)(lds + kc * 32768 + TSW(lrow, kk * 2)) = f2bf(g);
                }
        }
    };
    stashQ(acc00, 0, 0); stashQ(acc01, 0, 1); stashQ(acc10, 1, 0); stashQ(acc11, 1, 1);
    __syncthreads();

    bf16x8 wfrag[3][8];
#pragma unroll
    for (int tt = 0; tt < 3; ++tt) {
        const int t = tt * 16 + lr;
#pragma unroll
        for (int ks = 0; ks < 8; ++ks)
            wfrag[tt][ks] = *(const bf16x8*)(WT + (size_t)t * 3072 + n0 + ks * 32 + lk * 8);
    }

    f32x4 pacc[2][3];
#pragma unroll
    for (int i = 0; i < 2; ++i)
#pragma unroll
        for (int j = 0; j < 3; ++j) pacc[i][j] = (f32x4){0.f, 0.f, 0.f, 0.f};
#pragma unroll
    for (int rt2 = 0; rt2 < 2; ++rt2) {
        const int lrow = wid * 32 + rt2 * 16 + lr;
#pragma unroll
        for (int ks = 0; ks < 8; ++ks) {
            const int kc = ks >> 1, kh = ks & 1;
            bf16x8 af = *(const bf16x8*)(lds + kc * 32768 + TSW(lrow, kh * 64 + lk * 16));
#pragma unroll
            for (int tt = 0; tt < 3; ++tt)
                pacc[rt2][tt] = __builtin_amdgcn_mfma_f32_16x16x32_bf16(
                    af, wfrag[tt][ks], pacc[rt2][tt], 0, 0, 0);
        }
    }

    float* Pb = P + (size_t)Nt * NM * 48;
#pragma unroll
    for (int rt2 = 0; rt2 < 2; ++rt2)
#pragma unroll
        for (int tt = 0; tt < 3; ++tt)
#pragma unroll
            for (int r = 0; r < 4; ++r) {
                int row = Mt * 256 + wid * 32 + rt2 * 16 + lk * 4 + r;
                Pb[(size_t)row * 48 + tt * 16 + lr] = pacc[rt2][tt][r];
            }
}

// ---------------------------------------------------------------------------
// Kernel Cr: out = sum_Nt P[Nt] + b_crf, pads -10000.
// ---------------------------------------------------------------------------
__global__ __launch_bounds__(256) void kCr(const float* __restrict__ P,
                                           const float* __restrict__ bcrf,
                                           float* __restrict__ out) {
    const int g = blockIdx.x * 256 + threadIdx.x;
    const size_t STRIDE = (size_t)NM * 48;
#pragma unroll
    for (int s = 0; s < 12; ++s) {
        int flat = g * 12 + s;
        int row = flat / 48, t = flat - row * 48;
        float v = P[flat] + P[STRIDE + flat] + P[2*STRIDE + flat] + P[3*STRIDE + flat];
        if (t < NT)       out[(size_t)row * NLP + t] = v + bcrf[t];
        else if (t < NLP) out[(size_t)row * NLP + t] = -10000.0f;
    }
}

// ---------------------------------------------------------------------------
// Kernel Dm: segment matrix scan (round-13 proven).
// ---------------------------------------------------------------------------
__global__ __launch_bounds__(64) void kDm(const float* __restrict__ scores,
                                          const int* __restrict__ lens,
                                          const float* __restrict__ trans,
                                          float* __restrict__ Pm,
                                          float* __restrict__ Pc) {
    __shared__ float el_all[64 * 64];
    __shared__ __align__(16) char Mb[2 * 6144];

    const int lane = threadIdx.x;
    const int b    = blockIdx.x >> 3;
    const int s    = blockIdx.x & 7;
    const int lr   = lane & 15;
    const int lk   = lane >> 4;
    const int len  = lens[b];
    const int t0   = s * 64;
    const int nsteps = (len > t0) ? ((len - t0 < 64) ? (len - t0) : 64) : 0;
    const float* sb = scores + (size_t)b * NS * NLP;
    float* Pg = Pm + (size_t)(b * 8 + s) * 2304;

    if (nsteps == 0) {
        for (int j = 0; j < 36; ++j) Pg[j * 64 + lane] = 0.f;
        if (lane < 48) Pg[lane * 48 + lane] = 1.f;
        if (lane == 0) Pc[b * 8 + s] = 0.f;
        return;
    }

    for (int i = 0; i < 64; ++i) {
        float v = 0.f;
        if (i < nsteps && lane < NLP) v = __expf(sb[(size_t)(t0 + i) * NLP + lane]);
        el_all[i * 64 + lane] = v;
    }

    bf16x8 Tf[3][2];
#pragma unroll
    for (int tt = 0; tt < 3; ++tt)
#pragma unroll
        for (int ks = 0; ks < 2; ++ks) {
            const int row = tt * 16 + lr;
            unsigned int u[4];
#pragma unroll
            for (int e2 = 0; e2 < 4; ++e2) {
                int f0 = ks * 32 + lk * 8 + 2 * e2;
                float lo = (row < NLP && f0     < NLP) ? __expf(trans[row * NLP + f0])     : 0.f;
                float hi = (row < NLP && f0 + 1 < NLP) ? __expf(trans[row * NLP + f0 + 1]) : 0.f;
                u[e2] = pk2(lo, hi);
            }
            union { unsigned int uu[4]; bf16x8 v; } cv;
            cv.uu[0]=u[0]; cv.uu[1]=u[1]; cv.uu[2]=u[2]; cv.uu[3]=u[3];
            Tf[tt][ks] = cv.v;
        }

    for (int j = 0; j < 48; ++j)
        *(unsigned int*)(Mb + j * 256 + lane * 4) = 0;
    if (lane < 48) {
        int byte = (lane * 128 + lane * 2) ^ ((lane & 7) << 4);
        *(unsigned short*)(Mb + byte) = f2bf(1.0f);
    }

    float Cacc = 0.f;

    for (int i = 0; i < nsteps; ++i) {
        const int q = i & 1;
        const char* Mr = Mb + q * 6144;

        bf16x8 Bf[3][2];
#pragma unroll
        for (int ct = 0; ct < 3; ++ct) {
#pragma unroll
            for (int ks = 0; ks < 2; ++ks) {
                int col = ct * 16 + lr;
                int byte = (col * 128 + (ks * 32 + lk * 8) * 2) ^ ((col & 7) << 4);
                Bf[ct][ks] = *(const bf16x8*)(Mr + byte);
            }
        }
        f32x4 el4[3];
#pragma unroll
        for (int tt = 0; tt < 3; ++tt)
            el4[tt] = *(const f32x4*)&el_all[i * 64 + tt * 16 + lk * 4];

        f32x4 c[3][3];
#pragma unroll
        for (int tt = 0; tt < 3; ++tt)
#pragma unroll
            for (int ct = 0; ct < 3; ++ct) {
                c[tt][ct] = __builtin_amdgcn_mfma_f32_16x16x32_bf16(
                    Tf[tt][0], Bf[ct][0], (f32x4){0.f,0.f,0.f,0.f}, 0, 0, 0);
                c[tt][ct] = __builtin_amdgcn_mfma_f32_16x16x32_bf16(
                    Tf[tt][1], Bf[ct][1], c[tt][ct], 0, 0, 0);
            }
#pragma unroll
        for (int tt = 0; tt < 3; ++tt)
#pragma unroll
            for (int ct = 0; ct < 3; ++ct)
#pragma unroll
                for (int r = 0; r < 4; ++r)
                    c[tt][ct][r] *= el4[tt][r];

        if ((i & 3) == 3) {
            float sv = rl(c[0][0][0], 0);
            float rr = __builtin_amdgcn_rcpf(sv);
#pragma unroll
            for (int tt = 0; tt < 3; ++tt)
#pragma unroll
                for (int ct = 0; ct < 3; ++ct)
#pragma unroll
                    for (int r = 0; r < 4; ++r) c[tt][ct][r] *= rr;
            Cacc -= __logf(rr);
        }

        if (i == nsteps - 1) {
#pragma unroll
            for (int tt = 0; tt < 3; ++tt)
#pragma unroll
                for (int ct = 0; ct < 3; ++ct)
#pragma unroll
                    for (int r = 0; r < 4; ++r) {
                        int row = tt * 16 + lk * 4 + r;
                        int col = ct * 16 + lr;
                        Pg[row * 48 + col] = c[tt][ct][r];
                    }
        } else {
            char* Mw = Mb + (q ^ 1) * 6144;
#pragma unroll
            for (int tt = 0; tt < 3; ++tt)
#pragma unroll
                for (int ct = 0; ct < 3; ++ct) {
                    int col = ct * 16 + lr;
                    int k   = tt * 16 + lk * 4;
                    int byte = (col * 128 + k * 2) ^ ((col & 7) << 4);
                    *(uint2*)(Mw + byte) = make_uint2(pk2(c[tt][ct][0], c[tt][ct][1]),
                                                      pk2(c[tt][ct][2], c[tt][ct][3]));
                }
        }
    }

    if (lane == 0) Pc[b * 8 + s] = Cacc;
}

// ---------------------------------------------------------------------------
// Kernel Dc: combine (round-13 proven).
// ---------------------------------------------------------------------------
__global__ __launch_bounds__(256) void kDc(const float* __restrict__ scores,
                                           const int* __restrict__ labels,
                                           const int* __restrict__ lens,
                                           const float* __restrict__ trans,
                                           const float* __restrict__ Pm,
                                           const float* __restrict__ Pc,
                                           float* __restrict__ loss) {
    __shared__ float trL[39 * 41];
    __shared__ float gred[4];

    const int b    = blockIdx.x;
    const int tid  = threadIdx.x;
    const int lane = tid & 63;
    const int wid  = tid >> 6;
    const int len  = lens[b];
    const float* sb = scores + (size_t)b * NS * NLP;

    for (int idx = tid; idx < 39 * 39; idx += 256) {
        int to = idx / 39, f = idx - to * 39;
        trL[to * 41 + f] = trans[idx];
    }
    __syncthreads();

    float g = 0.0f;
    for (int t = tid; t < len; t += 256) g += sb[(size_t)t * NLP + labels[b * NS + t]];
    for (int i = tid; i <= len; i += 256) {
        int frm = (i == 0) ? 37 : labels[b * NS + i - 1];
        int to  = (i == len) ? 38 : labels[b * NS + i];
        g += trL[to * 41 + frm];
    }
#pragma unroll
    for (int off = 32; off > 0; off >>= 1) g += __shfl_xor(g, off, 64);
    if (lane == 0) gred[wid] = g;
    __syncthreads();

    if (wid != 0) return;

    const float gold = (gred[0] + gred[1]) + (gred[2] + gred[3]);
    const bool act48 = (lane < 48);

    const float* P0 = Pm + (size_t)b * 8 * 2304;
    float v = act48 ? P0[lane * 48 + 37] : 0.f;
    float C = Pc[b * 8];

    for (int s = 1; s < 8; ++s) {
        float as_[40];
#pragma unroll
        for (int f = 0; f < 40; ++f) as_[f] = rl(v, f);
        __builtin_amdgcn_sched_barrier(0);
        const float* Ps = Pm + (size_t)(b * 8 + s) * 2304;
        float c = 0.f;
        if (act48) {
            const float4* rowp = (const float4*)(Ps + lane * 48);
#pragma unroll
            for (int q = 0; q < 10; ++q) {
                float4 rv = rowp[q];
                c = fmaf(rv.x, as_[q*4+0], c);
                c = fmaf(rv.y, as_[q*4+1], c);
                c = fmaf(rv.z, as_[q*4+2], c);
                c = fmaf(rv.w, as_[q*4+3], c);
            }
        }
        float sv = rl(c, 0);
        float rr = __builtin_amdgcn_rcpf(sv);
        v = c * rr;
        C -= __logf(rr);
        C += Pc[b * 8 + s];
    }

    const float trEnd = (lane < NLP) ? trL[38 * 41 + lane] : 0.f;
    float aend = (lane < NLP && v > 0.f) ? C + __logf(v) + trEnd : -1e30f;
    float mx = aend;
#pragma unroll
    for (int off = 32; off > 0; off >>= 1) mx = fmaxf(mx, __shfl_xor(mx, off, 64));
    float es = (lane < NLP) ? __expf(aend - mx) : 0.f;
#pragma unroll
    for (int off = 32; off > 0; off >>= 1) es += __shfl_xor(es, off, 64);
    float norm = mx + __logf(es);

    if (lane == 0) loss[b] = gold - norm;
}

// ---------------------------------------------------------------------------
// Kernel B (fallback): reg-staged mixed GEMM (round-4 version).
// ---------------------------------------------------------------------------
__global__ __launch_bounds__(256) void kB(const float* __restrict__ h,
                                          const unsigned short* __restrict__ aware,
                                          const float* __restrict__ Wcat,
                                          const float* __restrict__ bcat,
                                          unsigned short* __restrict__ x2) {
    __shared__ __align__(16) char lds[16384];
    char* Asl = lds;
    char* Bsl = lds + 8192;

    const int tid  = threadIdx.x;
    const int lane = tid & 63;
    const int wid  = tid >> 6;
    const int wm   = (wid >> 1) * 64;
    const int wn   = (wid & 1) * 64;
    const int lr   = lane & 15;
    const int lk   = lane >> 4;

    const int id   = blockIdx.x;
    const int xcd  = id & 7;
    const int slot = id >> 3;
    const int m0   = (xcd * 16 + (slot >> 3)) * 128;
    const int n0   = (slot & 7) * 128;

    const int am = tid >> 1;
    const int ak = (tid & 1) * 16;
    const int bn = tid & 127;
    const int bk = (tid >> 7) * 16;

    f32x4 acc[4][4];
#pragma unroll
    for (int i = 0; i < 4; ++i)
#pragma unroll
        for (int j = 0; j < 4; ++j) acc[i][j] = (f32x4){0.f, 0.f, 0.f, 0.f};

    const float*          hrow = h     + (size_t)(m0 + am) * NH + ak;
    const unsigned short* arow = aware + (size_t)(m0 + am) * NH + ak;
    const float*          wcol = Wcat  + (size_t)bk * NH + n0 + bn;

    float hv[16];
    unsigned int aw[8];
    float wv[16];

    auto stage = [&](int kt) {
        const int region = kt >> 10;
        const int kb = kt & 1023;
        if (region != 1) {
            const float4* hp = (const float4*)(hrow + kb);
            float4 a = hp[0], b = hp[1], c = hp[2], d = hp[3];
            hv[0]=a.x; hv[1]=a.y; hv[2]=a.z; hv[3]=a.w;
            hv[4]=b.x; hv[5]=b.y; hv[6]=b.z; hv[7]=b.w;
            hv[8]=c.x; hv[9]=c.y; hv[10]=c.z; hv[11]=c.w;
            hv[12]=d.x; hv[13]=d.y; hv[14]=d.z; hv[15]=d.w;
        }
        if (region >= 1) {
            const uint4* ap = (const uint4*)(arow + kb);
            uint4 a0 = ap[0], a1 = ap[1];
            aw[0]=a0.x; aw[1]=a0.y; aw[2]=a0.z; aw[3]=a0.w;
            aw[4]=a1.x; aw[5]=a1.y; aw[6]=a1.z; aw[7]=a1.w;
        }
        {
            const float* wp = wcol + (size_t)kt * NH;
#pragma unroll
            for (int j = 0; j < 16; ++j) wv[j] = wp[(size_t)j * NH];
        }
    };

    auto writeStage = [&](int kt) {
        const int region = kt >> 10;
        unsigned int p[8];
        if (region == 0) {
#pragma unroll
            for (int i = 0; i < 8; ++i) p[i] = pk2(hv[2*i], hv[2*i+1]);
        } else if (region == 1) {
#pragma unroll
            for (int i = 0; i < 8; ++i) p[i] = aw[i];
        } else {
#pragma unroll
            for (int i = 0; i < 8; ++i) {
                float lo = hv[2*i]   * bf2f(aw[i] & 0xffffu);
                float hi = hv[2*i+1] * bf2f(aw[i] >> 16);
                p[i] = pk2(lo, hi);
            }
        }
        *(int4*)(Asl + SW64(am*64 + ak*2))      = make_int4(p[0], p[1], p[2], p[3]);
        *(int4*)(Asl + SW64(am*64 + ak*2 + 16)) = make_int4(p[4], p[5], p[6], p[7]);
        unsigned int q[8];
#pragma unroll
        for (int i = 0; i < 8; ++i) q[i] = pk2(wv[2*i], wv[2*i+1]);
        *(int4*)(Bsl + SW64(bn*64 + bk*2))      = make_int4(q[0], q[1], q[2], q[3]);
        *(int4*)(Bsl + SW64(bn*64 + bk*2 + 16)) = make_int4(q[4], q[5], q[6], q[7]);
    };

    stage(0);
    for (int kt = 0; kt < 3072; kt += 32) {
        __syncthreads();
        writeStage(kt);
        __syncthreads();
        if (kt + 32 < 3072) stage(kt + 32);

        bf16x8 af[4], bfr[4];
#pragma unroll
        for (int mf = 0; mf < 4; ++mf)
            af[mf] = *(const bf16x8*)(Asl + SW64((wm + mf*16 + lr)*64 + lk*16));
#pragma unroll
        for (int nf = 0; nf < 4; ++nf)
            bfr[nf] = *(const bf16x8*)(Bsl + SW64((wn + nf*16 + lr)*64 + lk*16));
#pragma unroll
        for (int mf = 0; mf < 4; ++mf)
#pragma unroll
            for (int nf = 0; nf < 4; ++nf)
                acc[mf][nf] = __builtin_amdgcn_mfma_f32_16x16x32_bf16(af[mf], bfr[nf], acc[mf][nf], 0, 0, 0);
    }

#pragma unroll
    for (int nf = 0; nf < 4; ++nf) {
        const int col = n0 + wn + nf*16 + lr;
        const float bc = bcat[col];
#pragma unroll
        for (int mf = 0; mf < 4; ++mf)
#pragma unroll
            for (int r = 0; r < 4; ++r) {
                size_t row = (size_t)(m0 + wm + mf*16 + lk*4 + r);
                float x = acc[mf][nf][r] + bc;
                float g = 0.5f * x * (1.0f + erff(x * 0.70710678118654752f));
                x2[row * NH + col] = f2bf(g);
            }
    }
}

// ---------------------------------------------------------------------------
// Kernel C (fallback): ner_scores = [x2 @ W_crf + b_crf, -10000, -10000]
// ---------------------------------------------------------------------------
__global__ __launch_bounds__(256) void kC(const unsigned short* __restrict__ x2,
                                          const float* __restrict__ Wcrf,
                                          const float* __restrict__ bcrf,
                                          float* __restrict__ out) {
    __shared__ __align__(16) char Asl[8192];
    __shared__ __align__(16) char Bsl[3072];

    const int tid  = threadIdx.x;
    const int lane = tid & 63;
    const int wid  = tid >> 6;
    const int lr   = lane & 15;
    const int lk   = lane >> 4;
    const int m0   = blockIdx.x * 128;
    const int am   = tid >> 1;
    const int ak   = (tid & 1) * 16;

    for (int i = tid; i < 192; i += 256) *(int4*)(Bsl + i*16) = make_int4(0, 0, 0, 0);

    f32x4 acc[2][3];
#pragma unroll
    for (int i = 0; i < 2; ++i)
#pragma unroll
        for (int j = 0; j < 3; ++j) acc[i][j] = (f32x4){0.f, 0.f, 0.f, 0.f};

    const unsigned short* xrow = x2 + (size_t)(m0 + am) * NH + ak;

    for (int kt = 0; kt < NH; kt += 32) {
        const uint4* xp = (const uint4*)(xrow + kt);
        uint4 x0 = xp[0], x1 = xp[1];
        float wv[5];
#pragma unroll
        for (int p = 0; p < 5; ++p) {
            int i = tid + p * 256;
            wv[p] = (i < 32*NT) ? Wcrf[(size_t)kt * NT + i] : 0.f;
        }
        __syncthreads();
        *(uint4*)(Asl + SW64(am*64 + ak*2))      = x0;
        *(uint4*)(Asl + SW64(am*64 + ak*2 + 16)) = x1;
#pragma unroll
        for (int p = 0; p < 5; ++p) {
            int i = tid + p * 256;
            if (i < 32*NT) {
                int kk = i / NT;
                int t  = i - kk * NT;
                *(unsigned short*)(Bsl + SW64(t*64 + kk*2)) = f2bf(wv[p]);
            }
        }
        __syncthreads();
        bf16x8 af[2], bfr[3];
#pragma unroll
        for (int mf = 0; mf < 2; ++mf)
            af[mf] = *(const bf16x8*)(Asl + SW64((wid*32 + mf*16 + lr)*64 + lk*16));
#pragma unroll
        for (int nf = 0; nf < 3; ++nf)
            bfr[nf] = *(const bf16x8*)(Bsl + SW64((nf*16 + lr)*64 + lk*16));
#pragma unroll
        for (int mf = 0; mf < 2; ++mf)
#pragma unroll
            for (int nf = 0; nf < 3; ++nf)
                acc[mf][nf] = __builtin_amdgcn_mfma_f32_16x16x32_bf16(af[mf], bfr[nf], acc[mf][nf], 0, 0, 0);
    }

#pragma unroll
    for (int nf = 0; nf < 3; ++nf) {
        const int t = nf*16 + lr;
        const float bc = (t < NT) ? bcrf[t] : 0.f;
#pragma unroll
        for (int mf = 0; mf < 2; ++mf)
#pragma unroll
            for (int r = 0; r < 4; ++r) {
                size_t row = (size_t)(m0 + wid*32 + mf*16 + lk*4 + r);
                if (t < NT)       out[row * NLP + t] = acc[mf][nf][r] + bc;
                else if (t < NLP) out[row * NLP + t] = -10000.0f;
            }
    }
}

// ---------------------------------------------------------------------------
// Kernel Dold (fallback): round-11 exp-domain scan, scores staged in LDS.
// ---------------------------------------------------------------------------
#define CRFSTEP(EL) do {                                   \
    float as_[37];                                         \
    _Pragma("unroll")                                      \
    for (int f_ = 0; f_ < 37; ++f_) as_[f_] = rl(a, f_);   \
    __builtin_amdgcn_sched_barrier(0);                     \
    float c0 = 0.f, c1 = 0.f, c2 = 0.f, c3 = 0.f;          \
    _Pragma("unroll")                                      \
    for (int f_ = 0; f_ < 36; f_ += 4) {                   \
        c0 = fmaf(as_[f_    ], trow[f_    ], c0);          \
        c1 = fmaf(as_[f_ + 1], trow[f_ + 1], c1);          \
        c2 = fmaf(as_[f_ + 2], trow[f_ + 2], c2);          \
        c3 = fmaf(as_[f_ + 3], trow[f_ + 3], c3);          \
    }                                                      \
    c0 = fmaf(as_[36], trow[36], c0);                      \
    a = (EL) * ((c0 + c1) + (c2 + c3));                    \
} while (0)

__global__ __launch_bounds__(256) void kDold(const float* __restrict__ scores,
                                             const int* __restrict__ labels,
                                             const int* __restrict__ lens,
                                             const float* __restrict__ trans,
                                             float* __restrict__ loss) {
    __shared__ float S[NS * NLP];
    __shared__ float trL[39 * 41];
    __shared__ int   labL[NS];
    __shared__ float gred[4];

    const int b    = blockIdx.x;
    const int tid  = threadIdx.x;
    const int lane = tid & 63;
    const int wid  = tid >> 6;
    const int len  = lens[b];
    const float* sb = scores + (size_t)b * NS * NLP;

    {
        const int n4 = (len * NLP + 3) >> 2;
        const float4* src = (const float4*)sb;
        float4* dst = (float4*)S;
        for (int i = tid; i < n4; i += 256) dst[i] = src[i];
    }
    for (int i = tid; i < NS; i += 256) labL[i] = labels[b * NS + i];
    for (int idx = tid; idx < 39 * 39; idx += 256) {
        int to = idx / 39, f = idx - to * 39;
        trL[to * 41 + f] = trans[idx];
    }
    __syncthreads();

    float g = 0.0f;
    for (int t = tid; t < len; t += 256) g += S[t * NLP + labL[t]];
    for (int i = tid; i <= len; i += 256) {
        int frm = (i == 0) ? 37 : labL[i - 1];
        int to  = (i == len) ? 38 : labL[i];
        g += trL[to * 41 + frm];
    }
#pragma unroll
    for (int off = 32; off > 0; off >>= 1) g += __shfl_xor(g, off, 64);
    if (lane == 0) gred[wid] = g;
    __syncthreads();

    if (wid != 0) return;

    const float gold = (gred[0] + gred[1]) + (gred[2] + gred[3]);

    const int myrow = (lane < 39) ? lane : 0;
    float trow[39];
#pragma unroll
    for (int f = 0; f < 39; ++f) trow[f] = __expf(trL[myrow * 41 + f]);
    const float trEnd = (lane < 39) ? trL[38 * 41 + lane] : 0.f;
    const bool act = (lane < 39);

    float l0 = act ? S[lane] : -10000.f;
    float a = act ? __expf(l0) * trow[37] : 0.f;
    float C = 0.0f;

    auto ldrow = [&](int r) {
        r = (r < len) ? r : (len - 1);
        return S[act ? (r * NLP + lane) : 0];
    };
    float lg0 = ldrow(1), lg1 = ldrow(2), lg2 = ldrow(3), lg3 = ldrow(4);

    int t = 1;
    for (; t + 3 < len; t += 4) {
        float e0 = __expf(lg0), e1 = __expf(lg1), e2 = __expf(lg2), e3 = __expf(lg3);
        lg0 = ldrow(t + 4); lg1 = ldrow(t + 5); lg2 = ldrow(t + 6); lg3 = ldrow(t + 7);
        CRFSTEP(e0); CRFSTEP(e1); CRFSTEP(e2); CRFSTEP(e3);
        float s = rl(a, 0);
        float rr = __builtin_amdgcn_rcpf(s);
        a *= rr; C -= __logf(rr);
    }
    for (; t < len; ++t) {
        float el = __expf(ldrow(t));
        CRFSTEP(el);
    }

    float aend = (act && a > 0.f) ? C + __logf(a) + trEnd : -1e30f;
    float mx = aend;
#pragma unroll
    for (int off = 32; off > 0; off >>= 1) mx = fmaxf(mx, __shfl_xor(mx, off, 64));
    float es = act ? __expf(aend - mx) : 0.0f;
#pragma unroll
    for (int off = 32; off > 0; off >>= 1) es += __shfl_xor(es, off, 64);
    float norm = mx + __logf(es);

    if (lane == 0) loss[b] = gold - norm;
}

// ---------------------------------------------------------------------------
extern "C" void kernel_launch(void* const* d_in, const int* in_sizes, int n_in,
                              void* d_out, int out_size, void* d_ws, size_t ws_size,
                              hipStream_t stream) {
    const float* h        = (const float*)d_in[0];
    const int* token_nums = (const int*)d_in[2];
    const int* labels     = (const int*)d_in[3];
    const float* bio      = (const float*)d_in[4];
    const float* Wcat     = (const float*)d_in[5];
    const float* bcat     = (const float*)d_in[6];
    const float* Wcrf     = (const float*)d_in[7];
    const float* bcrf     = (const float*)d_in[8];
    const float* trans    = (const float*)d_in[9];

    float* out = (float*)d_out;
    unsigned short* attn  = (unsigned short*)d_out;  // 2MB scratch, overwritten by kCr

    const size_t ASW_BYTES = (size_t)128 * 48 * 16384;        // 96 MB
    const size_t P_BYTES   = (size_t)4 * NM * 48 * 4;         // 12.6 MB
    const size_t WSW_BYTES = (size_t)8 * 48 * 16384;          // 6 MB
    const size_t WT_BYTES  = (size_t)48 * 3072 * 2;           // 288 KB
    const size_t PM_BYTES  = (size_t)NB * 8 * 2304 * 4;       // 2.36 MB
    const size_t PC_BYTES  = (size_t)NB * 8 * 4;              // 1 KB
    const bool fast = ws_size >= ASW_BYTES + P_BYTES + WSW_BYTES + WT_BYTES + PM_BYTES + PC_BYTES;

    if (fast) {
        char*  Asw = (char*)d_ws;
        float* P   = (float*)((char*)d_ws + ASW_BYTES);
        char*  Wsw = (char*)d_ws + ASW_BYTES + P_BYTES;
        unsigned short* WT = (unsigned short*)((char*)d_ws + ASW_BYTES + P_BYTES + WSW_BYTES);
        float* Pm  = (float*)((char*)d_ws + ASW_BYTES + P_BYTES + WSW_BYTES + WT_BYTES);
        float* Pc  = Pm + (size_t)NB * 8 * 2304;

        hipLaunchKernelGGL(kPre, dim3(548), dim3(512), 0, stream,
                           h, bio, Wcat, Wcrf, attn, Asw, Wsw, WT);
        hipLaunchKernelGGL(kA2f, dim3(NH / 128, NM / 128), dim3(256), 0, stream,
                           attn, bio, Asw);
        hipLaunchKernelGGL(kBf, dim3(256), dim3(512), 0, stream, Asw, Wsw, bcat, WT, P);
        hipLaunchKernelGGL(kCr, dim3(256), dim3(256), 0, stream, P, bcrf, out);
        hipLaunchKernelGGL(kDm, dim3(NB * 8), dim3(64), 0, stream, out, token_nums, trans,
                           Pm, Pc);
        hipLaunchKernelGGL(kDc, dim3(NB), dim3(256), 0, stream, out, labels, token_nums,
                           trans, Pm, Pc, out + (size_t)NM * NLP);
    } else {
        unsigned short* aware = (unsigned short*)d_ws;
        unsigned short* x2    = aware + (size_t)NM * NH;

        hipLaunchKernelGGL(kA1, dim3(NM / 128), dim3(512), 0, stream, h, bio, attn);
        hipLaunchKernelGGL(kA2, dim3(NH / 128, NM / 128), dim3(256), 0, stream, attn, bio, aware);
        hipLaunchKernelGGL(kB, dim3((NH / 128) * (NM / 128)), dim3(256), 0, stream,
                           h, aware, Wcat, bcat, x2);
        hipLaunchKernelGGL(kC, dim3(NM / 128), dim3(256), 0, stream, x2, Wcrf, bcrf, out);
        hipLaunchKernelGGL(kDold, dim3(NB), dim3(256), 0, stream, out, labels, token_nums,
                           trans, out + (size_t)NM * NLP);
    }
}